// Round 16
// baseline (877.853 us; speedup 1.0000x reference)
//
#include <hip/hip_runtime.h>

using u16 = unsigned short;
using u32 = unsigned int;

typedef __bf16 bf16x8 __attribute__((ext_vector_type(8)));
typedef float f32x4 __attribute__((ext_vector_type(4)));

typedef __attribute__((address_space(3))) u32 as3_u32;
typedef __attribute__((address_space(1))) const u32 as1_u32;

__device__ __forceinline__ u16 f2bf(float f) {
  u32 u = __builtin_bit_cast(u32, f);
  u = u + 0x7FFFu + ((u >> 16) & 1u);  // round-to-nearest-even
  return (u16)(u >> 16);
}
__device__ __forceinline__ float bf2f(u16 h) {
  return __builtin_bit_cast(float, (u32)h << 16);
}

// async global->LDS, 16B per lane; LDS dest = wave-uniform base + lane*16
__device__ __forceinline__ void gload16(const u16* g, u16* l) {
  __builtin_amdgcn_global_load_lds((as1_u32*)g, (as3_u32*)l, 16, 0, 0);
}

// ------------------------------------------------------------------
// transpose + f32->bf16 convert:  out[c][r] = bf16(in[r][c]) per layer z
// ------------------------------------------------------------------
__global__ __launch_bounds__(256) void transpose_f32_bf16(
    const float* __restrict__ in, u16* __restrict__ out, int R, int C) {
  __shared__ u16 tile[32][33];
  long zofs = (long)blockIdx.z * R * C;
  int c0 = blockIdx.x * 32, r0 = blockIdx.y * 32;
  for (int i = threadIdx.y; i < 32; i += 8)
    tile[i][threadIdx.x] = f2bf(in[zofs + (long)(r0 + i) * C + c0 + threadIdx.x]);
  __syncthreads();
  for (int i = threadIdx.y; i < 32; i += 8)
    out[zofs + (long)(c0 + i) * R + r0 + threadIdx.x] = tile[threadIdx.x][i];
}

// ------------------------------------------------------------------
// General bf16 GEMM, B transposed. 2-phase prefetch (dbuf LDS), BK=64,
// 4 waves, MI x NI frags of mfma 16x16x32. gload_lds w16 + XOR swizzle.
// VT=1: blocks with n0>=1024 also emit vT[n-1024][m] via LDS transpose.
// ------------------------------------------------------------------
template <int MI, int NI, int VT>
__global__ __launch_bounds__(256) void gemm_bt(
    const u16* __restrict__ A, int lda,
    const u16* __restrict__ B, int ldb,
    const float* __restrict__ bias,
    u16* __restrict__ outBf, int ldob,
    float* __restrict__ outF, int ldof, int accF,
    u16* __restrict__ vtOut,
    int M, int N, int K, int kChunks, float scale, int relu) {
  __shared__ u16 As[2][MI * 32 * 64];
  __shared__ u16 Bs[2][NI * 32 * 64];
  __shared__ u16 Ts[VT ? NI * 32 : 1][72];
  const int m0 = blockIdx.y * (MI * 32), n0 = blockIdx.x * (NI * 32);
  const int tid = threadIdx.x, lane = tid & 63, wid = tid >> 6;
  const int wr = (wid >> 1) * (MI * 16), wc = (wid & 1) * (NI * 16);
  const int r16 = lane & 15, kg = lane >> 4;

  const int lrow = lane >> 3;
  const int lchunk = (lane & 7) ^ lrow;

  f32x4 acc[MI][NI];
#pragma unroll
  for (int i = 0; i < MI; ++i)
#pragma unroll
    for (int j = 0; j < NI; ++j) acc[i][j] = f32x4{0.f, 0.f, 0.f, 0.f};

  const int kcs = K / kChunks;
  const int kbase = kcs * blockIdx.z;
  const int nkt = kcs / 64;

  auto STAGE = [&](int b, int k0) {
#pragma unroll
    for (int i = 0; i < MI; ++i) {
      const int r = i * 32 + wid * 8 + lrow;
      gload16(A + (long)(m0 + r) * lda + k0 + lchunk * 8,
              &As[b][wid * 512 + i * 2048]);
    }
#pragma unroll
    for (int j = 0; j < NI; ++j) {
      const int r = j * 32 + wid * 8 + lrow;
      gload16(B + (long)(n0 + r) * ldb + k0 + lchunk * 8,
              &Bs[b][wid * 512 + j * 2048]);
    }
  };

  STAGE(0, kbase);
  __syncthreads();

  for (int kt = 0; kt < nkt; ++kt) {
    const int cur = kt & 1;
    if (kt + 1 < nkt) STAGE(cur ^ 1, kbase + (kt + 1) * 64);

#pragma unroll
    for (int s = 0; s < 2; ++s) {
      bf16x8 af[MI], bfv[NI];
#pragma unroll
      for (int i = 0; i < MI; ++i) {
        const int r = wr + i * 16 + r16;
        af[i] = *reinterpret_cast<const bf16x8*>(
            &As[cur][r * 64 + (((s * 4 + kg) ^ (r & 7)) << 3)]);
      }
#pragma unroll
      for (int j = 0; j < NI; ++j) {
        const int r = wc + j * 16 + r16;
        bfv[j] = *reinterpret_cast<const bf16x8*>(
            &Bs[cur][r * 64 + (((s * 4 + kg) ^ (r & 7)) << 3)]);
      }
      __builtin_amdgcn_s_setprio(1);
#pragma unroll
      for (int i = 0; i < MI; ++i)
#pragma unroll
        for (int j = 0; j < NI; ++j)
          acc[i][j] = __builtin_amdgcn_mfma_f32_16x16x32_bf16(af[i], bfv[j], acc[i][j], 0, 0, 0);
      __builtin_amdgcn_s_setprio(0);
    }
    __syncthreads();
  }

  const int rg = (lane >> 4) * 4;
  const bool doVT = VT && (n0 >= 1024);
#pragma unroll
  for (int i = 0; i < MI; ++i) {
#pragma unroll
    for (int j = 0; j < NI; ++j) {
      int col = n0 + wc + j * 16 + r16;
      float bv = (bias && blockIdx.z == 0) ? bias[col] : 0.f;
#pragma unroll
      for (int r = 0; r < 4; ++r) {
        int row = m0 + wr + i * 16 + rg + r;
        float v = acc[i][j][r] * scale + bv;
        if (outF) {
          long idx = (long)row * ldof + col;
          if (accF) atomicAdd(&outF[idx], v);
          else outF[idx] = v;
        }
        if (outBf) {
          if (relu && v < 0.f) v = 0.f;
          u16 hv = f2bf(v);
          outBf[(long)row * ldob + col] = hv;
          if (doVT) Ts[wc + j * 16 + r16][wr + i * 16 + rg + r] = hv;
        }
      }
    }
  }

  if constexpr (VT) {
    if (doVT) {
      __syncthreads();
      const int d0 = n0 - 1024;
      constexpr int CH = MI * 4;
      constexpr int TOT = NI * 32 * CH;
#pragma unroll
      for (int c = 0; c < TOT / 256; ++c) {
        int idx = tid * (TOT / 256) + c;
        int drow = idx / CH, off = (idx % CH) * 8;
        *reinterpret_cast<uint4*>(vtOut + (long)(d0 + drow) * 2048 + m0 + off) =
            *reinterpret_cast<const uint4*>(&Ts[drow][off]);
      }
    }
  }
}

// ------------------------------------------------------------------
// Wout GEMM with fused split-combine:  x += normalize(oPart,lPart) @ WoutT + bout
// A-operand tile computed during staging (register 2-phase prefetch):
//   attn[t][d] = f2bf( (sum_s oPart_s[t][d]) / (sum_s l_s[h][t]) )
// — bit-identical to the old attn buffer. K-step 64 == head width.
// Grid (8, 32, 4 K-chunks); BM=BN=64; atomicAdd f32 epilogue.
// ------------------------------------------------------------------
__global__ __launch_bounds__(256) void gemm_wout(
    const u16* __restrict__ oPart, const float* __restrict__ lPart,
    const u16* __restrict__ B,  // WoutT, ldb = 512
    const float* __restrict__ bias, float* __restrict__ x) {
  __shared__ u16 As[2][64 * 64];
  __shared__ u16 Bs[2][64 * 64];
  const int m0 = blockIdx.y * 64, n0 = blockIdx.x * 64;
  const int tid = threadIdx.x, lane = tid & 63, wid = tid >> 6;
  const int wr = (wid >> 1) * 32, wc = (wid & 1) * 32;
  const int r16 = lane & 15, kg = lane >> 4;
  const int lrow = lane >> 3;
  const int lchunk = (lane & 7) ^ lrow;

  const int arow = tid >> 2;        // 0..63 (t offset)
  const int ac16 = (tid & 3) * 16;  // d chunk base

  uint4 a4[4][2];
  float lv[4];
  auto LOADA = [&](int k0) {
    const int h = k0 >> 6;
#pragma unroll
    for (int s = 0; s < 4; ++s) {
      const u16* op = oPart + ((long)s * 2048 + m0 + arow) * 512 + k0 + ac16;
      a4[s][0] = *reinterpret_cast<const uint4*>(op);
      a4[s][1] = *reinterpret_cast<const uint4*>(op + 8);
      lv[s] = lPart[(long)(s * 8 + h) * 2048 + m0 + arow];
    }
  };
  auto STOREA = [&](int b) {
    const float inv = 1.f / ((lv[0] + lv[1]) + (lv[2] + lv[3]));
#pragma unroll
    for (int c = 0; c < 2; ++c) {
      u16 out8[8];
#pragma unroll
      for (int e = 0; e < 8; ++e) {
        float acc = 0.f;
#pragma unroll
        for (int s = 0; s < 4; ++s)
          acc += bf2f(reinterpret_cast<const u16*>(&a4[s][c])[e]);
        out8[e] = f2bf(acc * inv);
      }
      const int cc = (tid & 3) * 2 + c;
      *reinterpret_cast<uint4*>(&As[b][arow * 64 + ((cc ^ (arow & 7)) << 3)]) =
          *reinterpret_cast<const uint4*>(out8);
    }
  };
  auto STAGEB = [&](int b, int k0) {
#pragma unroll
    for (int j = 0; j < 2; ++j) {
      const int r = j * 32 + wid * 8 + lrow;
      gload16(B + (long)(n0 + r) * 512 + k0 + lchunk * 8,
              &Bs[b][wid * 512 + j * 2048]);
    }
  };

  f32x4 acc[2][2];
#pragma unroll
  for (int i = 0; i < 2; ++i)
#pragma unroll
    for (int j = 0; j < 2; ++j) acc[i][j] = f32x4{0.f, 0.f, 0.f, 0.f};

  const int kbase = 128 * blockIdx.z;  // kcs = 128, 2 K-steps
  LOADA(kbase);
  STAGEB(0, kbase);
  STOREA(0);
  __syncthreads();

  for (int kt = 0; kt < 2; ++kt) {
    const int cur = kt & 1;
    if (kt == 0) {
      LOADA(kbase + 64);     // A prefetch into regs (in flight during compute)
      STAGEB(1, kbase + 64); // B prefetch via gload_lds
    }

#pragma unroll
    for (int s = 0; s < 2; ++s) {
      bf16x8 af[2], bfv[2];
#pragma unroll
      for (int i = 0; i < 2; ++i) {
        const int r = wr + i * 16 + r16;
        af[i] = *reinterpret_cast<const bf16x8*>(
            &As[cur][r * 64 + (((s * 4 + kg) ^ (r & 7)) << 3)]);
      }
#pragma unroll
      for (int j = 0; j < 2; ++j) {
        const int r = wc + j * 16 + r16;
        bfv[j] = *reinterpret_cast<const bf16x8*>(
            &Bs[cur][r * 64 + (((s * 4 + kg) ^ (r & 7)) << 3)]);
      }
      __builtin_amdgcn_s_setprio(1);
#pragma unroll
      for (int i = 0; i < 2; ++i)
#pragma unroll
        for (int j = 0; j < 2; ++j)
          acc[i][j] = __builtin_amdgcn_mfma_f32_16x16x32_bf16(af[i], bfv[j], acc[i][j], 0, 0, 0);
      __builtin_amdgcn_s_setprio(0);
    }
    if (kt == 0) STOREA(1);  // write prefetched A (regs drained by use)
    __syncthreads();
  }

  const int rg = (lane >> 4) * 4;
#pragma unroll
  for (int i = 0; i < 2; ++i) {
#pragma unroll
    for (int j = 0; j < 2; ++j) {
      int col = n0 + wc + j * 16 + r16;
      float bv = (blockIdx.z == 0) ? bias[col] : 0.f;
#pragma unroll
      for (int r = 0; r < 4; ++r) {
        int row = m0 + wr + i * 16 + rg + r;
        atomicAdd(&x[(long)row * 512 + col], acc[i][j][r] + bv);
      }
    }
  }
}

// ------------------------------------------------------------------
// Flash attention + FSMN slice. Grid (32, 8, 5):
//  z<4 : KV-split flash partials (bf16 oPart + lPart), as before.
//  z==4: FSMN block — x += v + depthwise_conv(v) for its 8-row strip.
//        (independent of attention; commutes with Wout's atomicAdds)
// ------------------------------------------------------------------
constexpr int AFP = 72;

__global__ __launch_bounds__(256, 4) void flash_attn_split(
    const u16* __restrict__ qkv, const u16* __restrict__ vT,
    u16* __restrict__ oPart, float* __restrict__ lPart,
    float* __restrict__ x, const float* __restrict__ fw) {
  __shared__ u16 Ks[2][64 * AFP];
  __shared__ u16 Vs[64 * AFP];
  __shared__ u16 Ps[4][16 * AFP];
  const int split = blockIdx.z;
  const int tid = threadIdx.x;

  if (split == 4) {
    // FSMN for rows [cell*8, cell*8+8), cols d, d+1
    const int cell = blockIdx.y * 32 + blockIdx.x;
    const int d = tid * 2;
    const u16* v = qkv + 1024 + d;
    float w0[11], w1[11];
#pragma unroll
    for (int j = 0; j < 11; ++j) {
      w0[j] = fw[d * 11 + j];
      w1[j] = fw[(d + 1) * 11 + j];
    }
    for (int rr = 0; rr < 8; ++rr) {
      const int t = cell * 8 + rr;
      float s0 = bf2f(v[(long)t * 1536]);
      float s1 = bf2f(v[(long)t * 1536 + 1]);
#pragma unroll
      for (int j = 0; j < 11; ++j) {
        int ts = t + j - 5;
        if (ts >= 0 && ts < 2048) {
          s0 += w0[j] * bf2f(v[(long)ts * 1536]);
          s1 += w1[j] * bf2f(v[(long)ts * 1536 + 1]);
        }
      }
      x[(long)t * 512 + d] += s0;
      x[(long)t * 512 + d + 1] += s1;
    }
    return;
  }

  const int h = blockIdx.y;
  const int q0 = blockIdx.x * 64;
  const int lane = tid & 63, wid = tid >> 6;
  const int r16 = lane & 15, kg8 = (lane >> 4) * 8;

  bf16x8 qa0, qa1;
  {
    union U { uint4 v; u16 hh[8]; } a, b;
    const u16* qrow = qkv + (long)(q0 + wid * 16 + r16) * 1536 + 64 * h;
    a.v = *reinterpret_cast<const uint4*>(qrow + kg8);
    b.v = *reinterpret_cast<const uint4*>(qrow + 32 + kg8);
#pragma unroll
    for (int i = 0; i < 8; ++i) {
      a.hh[i] = f2bf(bf2f(a.hh[i]) * 0.125f);
      b.hh[i] = f2bf(bf2f(b.hh[i]) * 0.125f);
    }
    qa0 = __builtin_bit_cast(bf16x8, a.v);
    qa1 = __builtin_bit_cast(bf16x8, b.v);
  }

  const int srow = tid >> 2;
  const int scol = (tid & 3) * 16;
  const u16* kgl = qkv + 512 + 64 * h + scol;
  const u16* vgl = vT + (long)(64 * h + srow) * 2048 + scol;

  uint4 kr0, kr1, vr0, vr1;
  auto LOAD = [&](int g) {
    const u16* kp = kgl + (long)(g * 64 + srow) * 1536;
    kr0 = *reinterpret_cast<const uint4*>(kp);
    kr1 = *reinterpret_cast<const uint4*>(kp + 8);
    const u16* vp = vgl + g * 64;
    vr0 = *reinterpret_cast<const uint4*>(vp);
    vr1 = *reinterpret_cast<const uint4*>(vp + 8);
  };
  auto STOREK = [&](int b) {
    *reinterpret_cast<uint4*>(&Ks[b][srow * AFP + scol]) = kr0;
    *reinterpret_cast<uint4*>(&Ks[b][srow * AFP + scol + 8]) = kr1;
  };
  auto STOREV = [&]() {
    *reinterpret_cast<uint4*>(&Vs[srow * AFP + scol]) = vr0;
    *reinterpret_cast<uint4*>(&Vs[srow * AFP + scol + 8]) = vr1;
  };

  f32x4 oacc[4];
#pragma unroll
  for (int j = 0; j < 4; ++j) oacc[j] = f32x4{0.f, 0.f, 0.f, 0.f};
  float lsum[4] = {0.f, 0.f, 0.f, 0.f};

  const int g0 = split * 8;
  LOAD(g0);
  STOREK(0);
  STOREV();
  __syncthreads();

  for (int t = 0; t < 8; ++t) {
    const int cur = t & 1;
    if (t < 7) LOAD(g0 + t + 1);

    f32x4 sacc[4];
#pragma unroll
    for (int j = 0; j < 4; ++j) sacc[j] = f32x4{0.f, 0.f, 0.f, 0.f};
    __builtin_amdgcn_s_setprio(1);
#pragma unroll
    for (int j = 0; j < 4; ++j) {
      bf16x8 b0 = *reinterpret_cast<const bf16x8*>(&Ks[cur][(j * 16 + r16) * AFP + kg8]);
      bf16x8 b1 = *reinterpret_cast<const bf16x8*>(&Ks[cur][(j * 16 + r16) * AFP + 32 + kg8]);
      sacc[j] = __builtin_amdgcn_mfma_f32_16x16x32_bf16(qa0, b0, sacc[j], 0, 0, 0);
      sacc[j] = __builtin_amdgcn_mfma_f32_16x16x32_bf16(qa1, b1, sacc[j], 0, 0, 0);
    }
    __builtin_amdgcn_s_setprio(0);

#pragma unroll
    for (int r = 0; r < 4; ++r) {
      float e0 = __expf(sacc[0][r]);
      float e1 = __expf(sacc[1][r]);
      float e2 = __expf(sacc[2][r]);
      float e3 = __expf(sacc[3][r]);
      lsum[r] += (e0 + e1) + (e2 + e3);
      int prow = (lane >> 4) * 4 + r;
      Ps[wid][prow * AFP + r16] = f2bf(e0);
      Ps[wid][prow * AFP + 16 + r16] = f2bf(e1);
      Ps[wid][prow * AFP + 32 + r16] = f2bf(e2);
      Ps[wid][prow * AFP + 48 + r16] = f2bf(e3);
    }

#pragma unroll
    for (int st = 0; st < 2; ++st) {
      bf16x8 pa = *reinterpret_cast<const bf16x8*>(&Ps[wid][r16 * AFP + st * 32 + kg8]);
      __builtin_amdgcn_s_setprio(1);
#pragma unroll
      for (int j = 0; j < 4; ++j) {
        bf16x8 bv = *reinterpret_cast<const bf16x8*>(&Vs[(j * 16 + r16) * AFP + st * 32 + kg8]);
        oacc[j] = __builtin_amdgcn_mfma_f32_16x16x32_bf16(pa, bv, oacc[j], 0, 0, 0);
      }
      __builtin_amdgcn_s_setprio(0);
    }

    if (t < 7) {
      STOREK(cur ^ 1);
      __syncthreads();
      STOREV();
      __syncthreads();
    }
  }

  const int rg = (lane >> 4) * 4;
#pragma unroll
  for (int r = 0; r < 4; ++r) {
    float ls = lsum[r];
#pragma unroll
    for (int o = 1; o < 16; o <<= 1) ls += __shfl_xor(ls, o);
    int row = q0 + wid * 16 + rg + r;
    if (r16 == 0) lPart[(long)(split * 8 + h) * 2048 + row] = ls;
#pragma unroll
    for (int j = 0; j < 4; ++j)
      oPart[(long)split * 2048 * 512 + (long)row * 512 + 64 * h + j * 16 + r16] =
          f2bf(oacc[j][r]);
  }
}

// ------------------------------------------------------------------
// LayerNorm over D=512, one block per row.
// ------------------------------------------------------------------
__device__ __forceinline__ void block_reduce2(float& s, float& ss) {
#pragma unroll
  for (int o = 32; o; o >>= 1) {
    s += __shfl_xor(s, o);
    ss += __shfl_xor(ss, o);
  }
  __shared__ float sm[8];
  int wid = threadIdx.x >> 6;
  if ((threadIdx.x & 63) == 0) {
    sm[wid] = s;
    sm[wid + 4] = ss;
  }
  __syncthreads();
  s = sm[0] + sm[1] + sm[2] + sm[3];
  ss = sm[4] + sm[5] + sm[6] + sm[7];
}

template <int OUTBF>
__global__ __launch_bounds__(256) void layernorm_k(
    const float* __restrict__ xin, const float* __restrict__ g,
    const float* __restrict__ bta, void* __restrict__ out) {
  const int row = blockIdx.x, tid = threadIdx.x;
  const float2 v = *reinterpret_cast<const float2*>(xin + (long)row * 512 + tid * 2);
  float s = v.x + v.y, ss = v.x * v.x + v.y * v.y;
  block_reduce2(s, ss);
  const float mean = s * (1.f / 512.f);
  const float var = ss * (1.f / 512.f) - mean * mean;
  const float inv = rsqrtf(var + 1e-5f);
  const float2 gg = *reinterpret_cast<const float2*>(g + tid * 2);
  const float2 bb = *reinterpret_cast<const float2*>(bta + tid * 2);
  const float y0 = (v.x - mean) * inv * gg.x + bb.x;
  const float y1 = (v.y - mean) * inv * gg.y + bb.y;
  if (OUTBF) {
    u16* o = (u16*)out + (long)row * 512 + tid * 2;
    o[0] = f2bf(y0);
    o[1] = f2bf(y1);
  } else {
    *reinterpret_cast<float2*>((float*)out + (long)row * 512 + tid * 2) =
        make_float2(y0, y1);
  }
}

// ------------------------------------------------------------------

extern "C" void kernel_launch(void* const* d_in, const int* in_sizes, int n_in,
                              void* d_out, int out_size, void* d_ws, size_t ws_size,
                              hipStream_t stream) {
  const float* in_x = (const float*)d_in[0];
  const float* ln1_g = (const float*)d_in[1];
  const float* ln1_b = (const float*)d_in[2];
  const float* Wqkv = (const float*)d_in[3];
  const float* bqkv = (const float*)d_in[4];
  const float* fsmn_w = (const float*)d_in[5];
  const float* Wout = (const float*)d_in[6];
  const float* bout = (const float*)d_in[7];
  const float* ln2_g = (const float*)d_in[8];
  const float* ln2_b = (const float*)d_in[9];
  const float* W1 = (const float*)d_in[10];
  const float* b1 = (const float*)d_in[11];
  const float* W2 = (const float*)d_in[12];
  const float* b2 = (const float*)d_in[13];
  const float* after_g = (const float*)d_in[14];
  const float* after_b = (const float*)d_in[15];

  const int T = 2048, D = 512, F = 2048, L = 8;

  char* p = (char*)d_ws;
  auto alloc = [&](size_t bytes) {
    char* r = p;
    p += (bytes + 255) & ~size_t(255);
    return r;
  };
  u16* WqkvT = (u16*)alloc(8L * 1536 * 512 * 2);
  u16* WoutT = (u16*)alloc(8L * 512 * 512 * 2);
  u16* W1T = (u16*)alloc(8L * 2048 * 512 * 2);
  u16* W2T = (u16*)alloc(8L * 512 * 2048 * 2);
  float* x = (float*)alloc((long)T * D * 4);
  u16* x1 = (u16*)alloc((long)T * D * 2);
  u16* qkv = (u16*)alloc((long)T * 1536 * 2);
  u16* vT = (u16*)alloc((long)D * T * 2);
  u16* hb = (u16*)alloc((long)T * F * 2);
  u16* oPart = (u16*)alloc(4L * T * D * 2);
  float* lPart = (float*)alloc(4L * 8 * T * 4);

  // ---- pre-pass: residual stream + bf16 transposed weights ----
  hipMemcpyAsync(x, in_x, (long)T * D * 4, hipMemcpyDeviceToDevice, stream);
  dim3 tb(32, 8);
  transpose_f32_bf16<<<dim3(1536 / 32, 512 / 32, 8), tb, 0, stream>>>(Wqkv, WqkvT, 512, 1536);
  transpose_f32_bf16<<<dim3(512 / 32, 512 / 32, 8), tb, 0, stream>>>(Wout, WoutT, 512, 512);
  transpose_f32_bf16<<<dim3(2048 / 32, 512 / 32, 8), tb, 0, stream>>>(W1, W1T, 512, 2048);
  transpose_f32_bf16<<<dim3(512 / 32, 2048 / 32, 8), tb, 0, stream>>>(W2, W2T, 2048, 512);

  for (int l = 0; l < L; ++l) {
    layernorm_k<1><<<T, 256, 0, stream>>>(x, ln1_g + 512 * l, ln1_b + 512 * l, x1);
    // QKV GEMM + fused vT emit   (BN=64: 768 blocks)
    gemm_bt<2, 2, 1><<<dim3(24, 32, 1), 256, 0, stream>>>(
        x1, 512, WqkvT + (long)l * 1536 * 512, 512, bqkv + 1536 * l,
        qkv, 1536, (float*)nullptr, 0, 0, vT, T, 1536, 512, 1, 1.f, 0);
    // flash attention partials (z<4) + FSMN slice (z==4)
    flash_attn_split<<<dim3(32, 8, 5), 256, 0, stream>>>(
        qkv, vT, oPart, lPart, x, fsmn_w + (long)l * 512 * 11);
    // x += normalize(oPart) @ Wout + bout   (fused combine; split-K=4)
    gemm_wout<<<dim3(8, 32, 4), 256, 0, stream>>>(
        oPart, lPart, WoutT + (long)l * 512 * 512, bout + 512 * l, x);
    layernorm_k<1><<<T, 256, 0, stream>>>(x, ln2_g + 512 * l, ln2_b + 512 * l, x1);
    // hb = relu(x1 @ W1 + b1)   (BN=64: 1024 blocks)
    gemm_bt<2, 2, 0><<<dim3(32, 32, 1), 256, 0, stream>>>(
        x1, 512, W1T + (long)l * 2048 * 512, 512, b1 + 2048 * l,
        hb, 2048, (float*)nullptr, 0, 0, (u16*)nullptr, T, 2048, 512, 1, 1.f, 1);
    // x += hb @ W2 + b2   (BN=64, split-K=4: 1024 blocks)
    gemm_bt<2, 2, 0><<<dim3(8, 32, 4), 256, 0, stream>>>(
        hb, 2048, W2T + (long)l * 512 * 2048, 2048, b2 + 512 * l,
        (u16*)nullptr, 0, x, 512, 1, (u16*)nullptr, T, 512, 2048, 4, 1.f, 0);
  }
  layernorm_k<0><<<T, 256, 0, stream>>>(x, after_g, after_b, (float*)d_out);
}

// Round 17
// 845.190 us; speedup vs baseline: 1.0386x; 1.0386x over previous
//
#include <hip/hip_runtime.h>

using u16 = unsigned short;
using u32 = unsigned int;

typedef __bf16 bf16x8 __attribute__((ext_vector_type(8)));
typedef float f32x4 __attribute__((ext_vector_type(4)));

typedef __attribute__((address_space(3))) u32 as3_u32;
typedef __attribute__((address_space(1))) const u32 as1_u32;

__device__ __forceinline__ u16 f2bf(float f) {
  u32 u = __builtin_bit_cast(u32, f);
  u = u + 0x7FFFu + ((u >> 16) & 1u);  // round-to-nearest-even
  return (u16)(u >> 16);
}
__device__ __forceinline__ float bf2f(u16 h) {
  return __builtin_bit_cast(float, (u32)h << 16);
}

// async global->LDS, 16B per lane; LDS dest = wave-uniform base + lane*16
__device__ __forceinline__ void gload16(const u16* g, u16* l) {
  __builtin_amdgcn_global_load_lds((as1_u32*)g, (as3_u32*)l, 16, 0, 0);
}

// ------------------------------------------------------------------
// All-weights transpose + f32->bf16, single dispatch.
// Per layer: Wqkv 768 blocks, Wout 256, W1 1024, W2 1024 = 3072.
// out[c][r] = bf16(in[r][c]) per (weight, layer) segment.
// ------------------------------------------------------------------
__global__ __launch_bounds__(256) void transpose_all(
    const float* __restrict__ w0, u16* __restrict__ o0,   // Wqkv 512x1536
    const float* __restrict__ w1, u16* __restrict__ o1,   // Wout 512x512
    const float* __restrict__ w2, u16* __restrict__ o2,   // W1   512x2048
    const float* __restrict__ w3, u16* __restrict__ o3) { // W2  2048x512
  __shared__ u16 tile[32][33];
  int id = blockIdx.x;
  const int layer = id / 3072;
  int r = id % 3072;
  const float* in;
  u16* out;
  int R, C, bx;
  if (r < 768)        { in = w0; out = o0; R = 512;  C = 1536; bx = 48; }
  else if (r < 1024)  { r -= 768;  in = w1; out = o1; R = 512;  C = 512;  bx = 16; }
  else if (r < 2048)  { r -= 1024; in = w2; out = o2; R = 512;  C = 2048; bx = 64; }
  else                { r -= 2048; in = w3; out = o3; R = 2048; C = 512;  bx = 16; }
  const long zofs = (long)layer * R * C;
  const int c0 = (r % bx) * 32, r0 = (r / bx) * 32;
  for (int i = threadIdx.y; i < 32; i += 8)
    tile[i][threadIdx.x] = f2bf(in[zofs + (long)(r0 + i) * C + c0 + threadIdx.x]);
  __syncthreads();
  for (int i = threadIdx.y; i < 32; i += 8)
    out[zofs + (long)(c0 + i) * R + r0 + threadIdx.x] = tile[threadIdx.x][i];
}

// ------------------------------------------------------------------
// General bf16 GEMM, B transposed. 2-phase prefetch (dbuf LDS), BK=64,
// 4 waves, MI x NI frags of mfma 16x16x32. gload_lds w16 + XOR swizzle.
// VT=1: blocks with n0>=1024 also emit vT[n-1024][m] via LDS transpose.
// blockIdx.z = K-chunk (split-K, atomicAdd f32 path).
// ------------------------------------------------------------------
template <int MI, int NI, int VT>
__global__ __launch_bounds__(256) void gemm_bt(
    const u16* __restrict__ A, int lda,
    const u16* __restrict__ B, int ldb,
    const float* __restrict__ bias,
    u16* __restrict__ outBf, int ldob,
    float* __restrict__ outF, int ldof, int accF,
    u16* __restrict__ vtOut,
    int M, int N, int K, int kChunks, float scale, int relu) {
  __shared__ u16 As[2][MI * 32 * 64];
  __shared__ u16 Bs[2][NI * 32 * 64];
  __shared__ u16 Ts[VT ? NI * 32 : 1][72];
  const int m0 = blockIdx.y * (MI * 32), n0 = blockIdx.x * (NI * 32);
  const int tid = threadIdx.x, lane = tid & 63, wid = tid >> 6;
  const int wr = (wid >> 1) * (MI * 16), wc = (wid & 1) * (NI * 16);
  const int r16 = lane & 15, kg = lane >> 4;

  const int lrow = lane >> 3;
  const int lchunk = (lane & 7) ^ lrow;

  f32x4 acc[MI][NI];
#pragma unroll
  for (int i = 0; i < MI; ++i)
#pragma unroll
    for (int j = 0; j < NI; ++j) acc[i][j] = f32x4{0.f, 0.f, 0.f, 0.f};

  const int kcs = K / kChunks;
  const int kbase = kcs * blockIdx.z;
  const int nkt = kcs / 64;

  auto STAGE = [&](int b, int k0) {
#pragma unroll
    for (int i = 0; i < MI; ++i) {
      const int r = i * 32 + wid * 8 + lrow;
      gload16(A + (long)(m0 + r) * lda + k0 + lchunk * 8,
              &As[b][wid * 512 + i * 2048]);
    }
#pragma unroll
    for (int j = 0; j < NI; ++j) {
      const int r = j * 32 + wid * 8 + lrow;
      gload16(B + (long)(n0 + r) * ldb + k0 + lchunk * 8,
              &Bs[b][wid * 512 + j * 2048]);
    }
  };

  STAGE(0, kbase);
  __syncthreads();

  for (int kt = 0; kt < nkt; ++kt) {
    const int cur = kt & 1;
    if (kt + 1 < nkt) STAGE(cur ^ 1, kbase + (kt + 1) * 64);

#pragma unroll
    for (int s = 0; s < 2; ++s) {
      bf16x8 af[MI], bfv[NI];
#pragma unroll
      for (int i = 0; i < MI; ++i) {
        const int r = wr + i * 16 + r16;
        af[i] = *reinterpret_cast<const bf16x8*>(
            &As[cur][r * 64 + (((s * 4 + kg) ^ (r & 7)) << 3)]);
      }
#pragma unroll
      for (int j = 0; j < NI; ++j) {
        const int r = wc + j * 16 + r16;
        bfv[j] = *reinterpret_cast<const bf16x8*>(
            &Bs[cur][r * 64 + (((s * 4 + kg) ^ (r & 7)) << 3)]);
      }
      __builtin_amdgcn_s_setprio(1);
#pragma unroll
      for (int i = 0; i < MI; ++i)
#pragma unroll
        for (int j = 0; j < NI; ++j)
          acc[i][j] = __builtin_amdgcn_mfma_f32_16x16x32_bf16(af[i], bfv[j], acc[i][j], 0, 0, 0);
      __builtin_amdgcn_s_setprio(0);
    }
    __syncthreads();
  }

  const int rg = (lane >> 4) * 4;
  const bool doVT = VT && (n0 >= 1024);
#pragma unroll
  for (int i = 0; i < MI; ++i) {
#pragma unroll
    for (int j = 0; j < NI; ++j) {
      int col = n0 + wc + j * 16 + r16;
      float bv = (bias && blockIdx.z == 0) ? bias[col] : 0.f;
#pragma unroll
      for (int r = 0; r < 4; ++r) {
        int row = m0 + wr + i * 16 + rg + r;
        float v = acc[i][j][r] * scale + bv;
        if (outF) {
          long idx = (long)row * ldof + col;
          if (accF) atomicAdd(&outF[idx], v);
          else outF[idx] = v;
        }
        if (outBf) {
          if (relu && v < 0.f) v = 0.f;
          u16 hv = f2bf(v);
          outBf[(long)row * ldob + col] = hv;
          if (doVT) Ts[wc + j * 16 + r16][wr + i * 16 + rg + r] = hv;
        }
      }
    }
  }

  if constexpr (VT) {
    if (doVT) {
      __syncthreads();
      const int d0 = n0 - 1024;
      constexpr int CH = MI * 4;
      constexpr int TOT = NI * 32 * CH;
#pragma unroll
      for (int c = 0; c < TOT / 256; ++c) {
        int idx = tid * (TOT / 256) + c;
        int drow = idx / CH, off = (idx % CH) * 8;
        *reinterpret_cast<uint4*>(vtOut + (long)(d0 + drow) * 2048 + m0 + off) =
            *reinterpret_cast<const uint4*>(&Ts[drow][off]);
      }
    }
  }
}

// ------------------------------------------------------------------
// Flash attention, cooperative 4-wave blocks, no-max softmax.
// K double-buffered, V single-buffered. Grid (32,8,4). bf16 partials.
// ------------------------------------------------------------------
constexpr int AFP = 72;

__global__ __launch_bounds__(256, 4) void flash_attn_split(
    const u16* __restrict__ qkv, const u16* __restrict__ vT,
    u16* __restrict__ oPart, float* __restrict__ lPart) {
  __shared__ u16 Ks[2][64 * AFP];
  __shared__ u16 Vs[64 * AFP];
  __shared__ u16 Ps[4][16 * AFP];
  const int h = blockIdx.y;
  const int q0 = blockIdx.x * 64;
  const int split = blockIdx.z;
  const int tid = threadIdx.x;
  const int lane = tid & 63, wid = tid >> 6;
  const int r16 = lane & 15, kg8 = (lane >> 4) * 8;

  bf16x8 qa0, qa1;
  {
    union U { uint4 v; u16 hh[8]; } a, b;
    const u16* qrow = qkv + (long)(q0 + wid * 16 + r16) * 1536 + 64 * h;
    a.v = *reinterpret_cast<const uint4*>(qrow + kg8);
    b.v = *reinterpret_cast<const uint4*>(qrow + 32 + kg8);
#pragma unroll
    for (int i = 0; i < 8; ++i) {
      a.hh[i] = f2bf(bf2f(a.hh[i]) * 0.125f);
      b.hh[i] = f2bf(bf2f(b.hh[i]) * 0.125f);
    }
    qa0 = __builtin_bit_cast(bf16x8, a.v);
    qa1 = __builtin_bit_cast(bf16x8, b.v);
  }

  const int srow = tid >> 2;
  const int scol = (tid & 3) * 16;
  const u16* kgl = qkv + 512 + 64 * h + scol;
  const u16* vgl = vT + (long)(64 * h + srow) * 2048 + scol;

  uint4 kr0, kr1, vr0, vr1;
  auto LOAD = [&](int g) {
    const u16* kp = kgl + (long)(g * 64 + srow) * 1536;
    kr0 = *reinterpret_cast<const uint4*>(kp);
    kr1 = *reinterpret_cast<const uint4*>(kp + 8);
    const u16* vp = vgl + g * 64;
    vr0 = *reinterpret_cast<const uint4*>(vp);
    vr1 = *reinterpret_cast<const uint4*>(vp + 8);
  };
  auto STOREK = [&](int b) {
    *reinterpret_cast<uint4*>(&Ks[b][srow * AFP + scol]) = kr0;
    *reinterpret_cast<uint4*>(&Ks[b][srow * AFP + scol + 8]) = kr1;
  };
  auto STOREV = [&]() {
    *reinterpret_cast<uint4*>(&Vs[srow * AFP + scol]) = vr0;
    *reinterpret_cast<uint4*>(&Vs[srow * AFP + scol + 8]) = vr1;
  };

  f32x4 oacc[4];
#pragma unroll
  for (int j = 0; j < 4; ++j) oacc[j] = f32x4{0.f, 0.f, 0.f, 0.f};
  float lsum[4] = {0.f, 0.f, 0.f, 0.f};

  const int g0 = split * 8;
  LOAD(g0);
  STOREK(0);
  STOREV();
  __syncthreads();

  for (int t = 0; t < 8; ++t) {
    const int cur = t & 1;
    if (t < 7) LOAD(g0 + t + 1);

    f32x4 sacc[4];
#pragma unroll
    for (int j = 0; j < 4; ++j) sacc[j] = f32x4{0.f, 0.f, 0.f, 0.f};
    __builtin_amdgcn_s_setprio(1);
#pragma unroll
    for (int j = 0; j < 4; ++j) {
      bf16x8 b0 = *reinterpret_cast<const bf16x8*>(&Ks[cur][(j * 16 + r16) * AFP + kg8]);
      bf16x8 b1 = *reinterpret_cast<const bf16x8*>(&Ks[cur][(j * 16 + r16) * AFP + 32 + kg8]);
      sacc[j] = __builtin_amdgcn_mfma_f32_16x16x32_bf16(qa0, b0, sacc[j], 0, 0, 0);
      sacc[j] = __builtin_amdgcn_mfma_f32_16x16x32_bf16(qa1, b1, sacc[j], 0, 0, 0);
    }
    __builtin_amdgcn_s_setprio(0);

#pragma unroll
    for (int r = 0; r < 4; ++r) {
      float e0 = __expf(sacc[0][r]);
      float e1 = __expf(sacc[1][r]);
      float e2 = __expf(sacc[2][r]);
      float e3 = __expf(sacc[3][r]);
      lsum[r] += (e0 + e1) + (e2 + e3);
      int prow = (lane >> 4) * 4 + r;
      Ps[wid][prow * AFP + r16] = f2bf(e0);
      Ps[wid][prow * AFP + 16 + r16] = f2bf(e1);
      Ps[wid][prow * AFP + 32 + r16] = f2bf(e2);
      Ps[wid][prow * AFP + 48 + r16] = f2bf(e3);
    }

#pragma unroll
    for (int st = 0; st < 2; ++st) {
      bf16x8 pa = *reinterpret_cast<const bf16x8*>(&Ps[wid][r16 * AFP + st * 32 + kg8]);
      __builtin_amdgcn_s_setprio(1);
#pragma unroll
      for (int j = 0; j < 4; ++j) {
        bf16x8 bv = *reinterpret_cast<const bf16x8*>(&Vs[(j * 16 + r16) * AFP + st * 32 + kg8]);
        oacc[j] = __builtin_amdgcn_mfma_f32_16x16x32_bf16(pa, bv, oacc[j], 0, 0, 0);
      }
      __builtin_amdgcn_s_setprio(0);
    }

    if (t < 7) {
      STOREK(cur ^ 1);
      __syncthreads();
      STOREV();
      __syncthreads();
    }
  }

  const int rg = (lane >> 4) * 4;
#pragma unroll
  for (int r = 0; r < 4; ++r) {
    float ls = lsum[r];
#pragma unroll
    for (int o = 1; o < 16; o <<= 1) ls += __shfl_xor(ls, o);
    int row = q0 + wid * 16 + rg + r;
    if (r16 == 0) lPart[(long)(split * 8 + h) * 2048 + row] = ls;
#pragma unroll
    for (int j = 0; j < 4; ++j)
      oPart[(long)split * 2048 * 512 + (long)row * 512 + 64 * h + j * 16 + r16] =
          f2bf(oacc[j][r]);
  }
}

// ------------------------------------------------------------------
// Fused: combine KV-split bf16 partials -> attn bf16, AND x += fsmn(v).
// ------------------------------------------------------------------
__global__ __launch_bounds__(256) void attn_norm_fsmn(
    const u16* __restrict__ oPart, const float* __restrict__ lPart,
    u16* __restrict__ attn, float* __restrict__ x,
    const u16* __restrict__ qkv, const float* __restrict__ fw) {
  const int t = blockIdx.x;
  const int d = threadIdx.x * 2;
  const int h = d >> 6;
  float l = 0.f;
#pragma unroll
  for (int s = 0; s < 4; ++s) l += lPart[(long)(s * 8 + h) * 2048 + t];
  float ox = 0.f, oy = 0.f;
#pragma unroll
  for (int s = 0; s < 4; ++s) {
    const u32 v = *reinterpret_cast<const u32*>(
        oPart + (long)s * 2048 * 512 + (long)t * 512 + d);
    ox += bf2f((u16)v);
    oy += bf2f((u16)(v >> 16));
  }
  const float inv = 1.f / l;
  u16* out = attn + (long)t * 512 + d;
  out[0] = f2bf(ox * inv);
  out[1] = f2bf(oy * inv);

  const u16* v = qkv + 1024 + d;
  float s0 = bf2f(v[(long)t * 1536]);
  float s1 = bf2f(v[(long)t * 1536 + 1]);
#pragma unroll
  for (int j = 0; j < 11; ++j) {
    int ts = t + j - 5;
    if (ts >= 0 && ts < 2048) {
      float w0 = fw[d * 11 + j], w1 = fw[(d + 1) * 11 + j];
      s0 += w0 * bf2f(v[(long)ts * 1536]);
      s1 += w1 * bf2f(v[(long)ts * 1536 + 1]);
    }
  }
  x[(long)t * 512 + d] += s0;
  x[(long)t * 512 + d + 1] += s1;
}

// ------------------------------------------------------------------
// LayerNorm over D=512, one block per row.
// ------------------------------------------------------------------
__device__ __forceinline__ void block_reduce2(float& s, float& ss) {
#pragma unroll
  for (int o = 32; o; o >>= 1) {
    s += __shfl_xor(s, o);
    ss += __shfl_xor(ss, o);
  }
  __shared__ float sm[8];
  int wid = threadIdx.x >> 6;
  if ((threadIdx.x & 63) == 0) {
    sm[wid] = s;
    sm[wid + 4] = ss;
  }
  __syncthreads();
  s = sm[0] + sm[1] + sm[2] + sm[3];
  ss = sm[4] + sm[5] + sm[6] + sm[7];
}

template <int OUTBF>
__global__ __launch_bounds__(256) void layernorm_k(
    const float* __restrict__ xin, const float* __restrict__ g,
    const float* __restrict__ bta, void* __restrict__ out) {
  const int row = blockIdx.x, tid = threadIdx.x;
  const float2 v = *reinterpret_cast<const float2*>(xin + (long)row * 512 + tid * 2);
  float s = v.x + v.y, ss = v.x * v.x + v.y * v.y;
  block_reduce2(s, ss);
  const float mean = s * (1.f / 512.f);
  const float var = ss * (1.f / 512.f) - mean * mean;
  const float inv = rsqrtf(var + 1e-5f);
  const float2 gg = *reinterpret_cast<const float2*>(g + tid * 2);
  const float2 bb = *reinterpret_cast<const float2*>(bta + tid * 2);
  const float y0 = (v.x - mean) * inv * gg.x + bb.x;
  const float y1 = (v.y - mean) * inv * gg.y + bb.y;
  if (OUTBF) {
    u16* o = (u16*)out + (long)row * 512 + tid * 2;
    o[0] = f2bf(y0);
    o[1] = f2bf(y1);
  } else {
    *reinterpret_cast<float2*>((float*)out + (long)row * 512 + tid * 2) =
        make_float2(y0, y1);
  }
}

// ------------------------------------------------------------------

extern "C" void kernel_launch(void* const* d_in, const int* in_sizes, int n_in,
                              void* d_out, int out_size, void* d_ws, size_t ws_size,
                              hipStream_t stream) {
  const float* in_x = (const float*)d_in[0];
  const float* ln1_g = (const float*)d_in[1];
  const float* ln1_b = (const float*)d_in[2];
  const float* Wqkv = (const float*)d_in[3];
  const float* bqkv = (const float*)d_in[4];
  const float* fsmn_w = (const float*)d_in[5];
  const float* Wout = (const float*)d_in[6];
  const float* bout = (const float*)d_in[7];
  const float* ln2_g = (const float*)d_in[8];
  const float* ln2_b = (const float*)d_in[9];
  const float* W1 = (const float*)d_in[10];
  const float* b1 = (const float*)d_in[11];
  const float* W2 = (const float*)d_in[12];
  const float* b2 = (const float*)d_in[13];
  const float* after_g = (const float*)d_in[14];
  const float* after_b = (const float*)d_in[15];

  const int T = 2048, D = 512, F = 2048, L = 8;

  char* p = (char*)d_ws;
  auto alloc = [&](size_t bytes) {
    char* r = p;
    p += (bytes + 255) & ~size_t(255);
    return r;
  };
  u16* WqkvT = (u16*)alloc(8L * 1536 * 512 * 2);
  u16* WoutT = (u16*)alloc(8L * 512 * 512 * 2);
  u16* W1T = (u16*)alloc(8L * 2048 * 512 * 2);
  u16* W2T = (u16*)alloc(8L * 512 * 2048 * 2);
  float* x = (float*)alloc((long)T * D * 4);
  u16* x1 = (u16*)alloc((long)T * D * 2);
  u16* qkv = (u16*)alloc((long)T * 1536 * 2);
  u16* vT = (u16*)alloc((long)D * T * 2);
  u16* attn = (u16*)alloc((long)T * D * 2);
  u16* hb = (u16*)alloc((long)T * F * 2);
  u16* oPart = (u16*)alloc(4L * T * D * 2);
  float* lPart = (float*)alloc(4L * 8 * T * 4);

  // ---- pre-pass: residual stream + bf16 transposed weights (1 dispatch) ----
  hipMemcpyAsync(x, in_x, (long)T * D * 4, hipMemcpyDeviceToDevice, stream);
  transpose_all<<<dim3(3072 * 8, 1, 1), dim3(32, 8), 0, stream>>>(
      Wqkv, WqkvT, Wout, WoutT, W1, W1T, W2, W2T);

  for (int l = 0; l < L; ++l) {
    layernorm_k<1><<<T, 256, 0, stream>>>(x, ln1_g + 512 * l, ln1_b + 512 * l, x1);
    // QKV GEMM + fused vT emit   (BN=64: 768 blocks)
    gemm_bt<2, 2, 1><<<dim3(24, 32, 1), 256, 0, stream>>>(
        x1, 512, WqkvT + (long)l * 1536 * 512, 512, bqkv + 1536 * l,
        qkv, 1536, (float*)nullptr, 0, 0, vT, T, 1536, 512, 1, 1.f, 0);
    // flash attention partials (KV-split 4)
    flash_attn_split<<<dim3(32, 8, 4), 256, 0, stream>>>(qkv, vT, oPart, lPart);
    // combine partials -> attn, and x += fsmn(v)
    attn_norm_fsmn<<<T, 256, 0, stream>>>(oPart, lPart, attn, x, qkv,
                                          fsmn_w + (long)l * 512 * 11);
    // x += attn @ Wout + bout   (BN=64, split-K=4: 1024 blocks)
    gemm_bt<2, 2, 0><<<dim3(8, 32, 4), 256, 0, stream>>>(
        attn, 512, WoutT + (long)l * 512 * 512, 512, bout + 512 * l,
        (u16*)nullptr, 0, x, 512, 1, (u16*)nullptr, T, 512, 512, 4, 1.f, 0);
    layernorm_k<1><<<T, 256, 0, stream>>>(x, ln2_g + 512 * l, ln2_b + 512 * l, x1);
    // hb = relu(x1 @ W1 + b1)   (BN=64: 1024 blocks)
    gemm_bt<2, 2, 0><<<dim3(32, 32, 1), 256, 0, stream>>>(
        x1, 512, W1T + (long)l * 2048 * 512, 512, b1 + 2048 * l,
        hb, 2048, (float*)nullptr, 0, 0, (u16*)nullptr, T, 2048, 512, 1, 1.f, 1);
    // x += hb @ W2 + b2   (BN=64, split-K=4: 1024 blocks)
    gemm_bt<2, 2, 0><<<dim3(8, 32, 4), 256, 0, stream>>>(
        hb, 2048, W2T + (long)l * 512 * 2048, 2048, b2 + 512 * l,
        (u16*)nullptr, 0, x, 512, 1, (u16*)nullptr, T, 512, 2048, 4, 1.f, 0);
  }
  layernorm_k<0><<<T, 256, 0, stream>>>(x, after_g, after_b, (float*)d_out);
}

// Round 18
// 838.418 us; speedup vs baseline: 1.0470x; 1.0081x over previous
//
#include <hip/hip_runtime.h>

using u16 = unsigned short;
using u32 = unsigned int;

typedef __bf16 bf16x8 __attribute__((ext_vector_type(8)));
typedef float f32x4 __attribute__((ext_vector_type(4)));

typedef __attribute__((address_space(3))) u32 as3_u32;
typedef __attribute__((address_space(1))) const u32 as1_u32;

__device__ __forceinline__ u16 f2bf(float f) {
  u32 u = __builtin_bit_cast(u32, f);
  u = u + 0x7FFFu + ((u >> 16) & 1u);  // round-to-nearest-even
  return (u16)(u >> 16);
}
__device__ __forceinline__ float bf2f(u16 h) {
  return __builtin_bit_cast(float, (u32)h << 16);
}

// async global->LDS, 16B per lane; LDS dest = wave-uniform base + lane*16
__device__ __forceinline__ void gload16(const u16* g, u16* l) {
  __builtin_amdgcn_global_load_lds((as1_u32*)g, (as3_u32*)l, 16, 0, 0);
}

// ------------------------------------------------------------------
// All-weights transpose + f32->bf16, single dispatch, vectorized.
// 64x64 tiles; float4 loads, LDS round-trip, uint4 coalesced writes.
// Per layer: Wqkv 192 tiles, Wout 64, W1 256, W2 256 = 768.
// ------------------------------------------------------------------
__global__ __launch_bounds__(256) void transpose_all(
    const float* __restrict__ w0, u16* __restrict__ o0,   // Wqkv 512x1536
    const float* __restrict__ w1, u16* __restrict__ o1,   // Wout 512x512
    const float* __restrict__ w2, u16* __restrict__ o2,   // W1   512x2048
    const float* __restrict__ w3, u16* __restrict__ o3) { // W2  2048x512
  __shared__ u16 tile[64][66];  // pad 66: phase-1 writes 2-way, phase-2 reads 4-way
  int id = blockIdx.x;
  const int layer = id / 768;
  int r = id % 768;
  const float* in;
  u16* out;
  int R, C, bx;
  if (r < 192)       { in = w0; out = o0; R = 512;  C = 1536; bx = 24; }
  else if (r < 256)  { r -= 192; in = w1; out = o1; R = 512;  C = 512;  bx = 8;  }
  else if (r < 512)  { r -= 256; in = w2; out = o2; R = 512;  C = 2048; bx = 32; }
  else               { r -= 512; in = w3; out = o3; R = 2048; C = 512;  bx = 8;  }
  const long zofs = (long)layer * R * C;
  const int c0 = (r % bx) * 64, r0 = (r / bx) * 64;
  const int tid = threadIdx.x;

  // phase 1: 1024 float4 loads (coalesced), bf16 convert, normal LDS store
#pragma unroll
  for (int k = 0; k < 4; ++k) {
    int it = tid + k * 256;
    int row = it >> 4, c4 = (it & 15) * 4;
    float4 v = *reinterpret_cast<const float4*>(
        in + zofs + (long)(r0 + row) * C + c0 + c4);
    tile[row][c4 + 0] = f2bf(v.x);
    tile[row][c4 + 1] = f2bf(v.y);
    tile[row][c4 + 2] = f2bf(v.z);
    tile[row][c4 + 3] = f2bf(v.w);
  }
  __syncthreads();

  // phase 2: gather 8 rows per thread-item, pack uint4, coalesced store
#pragma unroll
  for (int k = 0; k < 2; ++k) {
    int it = tid + k * 256;
    int cc = it >> 3, r8 = (it & 7) * 8;
    u16 tmp[8];
#pragma unroll
    for (int e = 0; e < 8; ++e) tmp[e] = tile[r8 + e][cc];
    *reinterpret_cast<uint4*>(out + zofs + (long)(c0 + cc) * R + r0 + r8) =
        *reinterpret_cast<const uint4*>(tmp);
  }
}

// ------------------------------------------------------------------
// General bf16 GEMM, B transposed. 2-phase prefetch (dbuf LDS), BK=64,
// 4 waves, MI x NI frags of mfma 16x16x32. gload_lds w16 + XOR swizzle.
// VT=1: blocks with n0>=1024 also emit vT[n-1024][m] via LDS transpose.
// blockIdx.z = K-chunk (split-K, atomicAdd f32 path).
// ------------------------------------------------------------------
template <int MI, int NI, int VT>
__global__ __launch_bounds__(256) void gemm_bt(
    const u16* __restrict__ A, int lda,
    const u16* __restrict__ B, int ldb,
    const float* __restrict__ bias,
    u16* __restrict__ outBf, int ldob,
    float* __restrict__ outF, int ldof, int accF,
    u16* __restrict__ vtOut,
    int M, int N, int K, int kChunks, float scale, int relu) {
  __shared__ u16 As[2][MI * 32 * 64];
  __shared__ u16 Bs[2][NI * 32 * 64];
  __shared__ u16 Ts[VT ? NI * 32 : 1][72];
  const int m0 = blockIdx.y * (MI * 32), n0 = blockIdx.x * (NI * 32);
  const int tid = threadIdx.x, lane = tid & 63, wid = tid >> 6;
  const int wr = (wid >> 1) * (MI * 16), wc = (wid & 1) * (NI * 16);
  const int r16 = lane & 15, kg = lane >> 4;

  const int lrow = lane >> 3;
  const int lchunk = (lane & 7) ^ lrow;

  f32x4 acc[MI][NI];
#pragma unroll
  for (int i = 0; i < MI; ++i)
#pragma unroll
    for (int j = 0; j < NI; ++j) acc[i][j] = f32x4{0.f, 0.f, 0.f, 0.f};

  const int kcs = K / kChunks;
  const int kbase = kcs * blockIdx.z;
  const int nkt = kcs / 64;

  auto STAGE = [&](int b, int k0) {
#pragma unroll
    for (int i = 0; i < MI; ++i) {
      const int r = i * 32 + wid * 8 + lrow;
      gload16(A + (long)(m0 + r) * lda + k0 + lchunk * 8,
              &As[b][wid * 512 + i * 2048]);
    }
#pragma unroll
    for (int j = 0; j < NI; ++j) {
      const int r = j * 32 + wid * 8 + lrow;
      gload16(B + (long)(n0 + r) * ldb + k0 + lchunk * 8,
              &Bs[b][wid * 512 + j * 2048]);
    }
  };

  STAGE(0, kbase);
  __syncthreads();

  for (int kt = 0; kt < nkt; ++kt) {
    const int cur = kt & 1;
    if (kt + 1 < nkt) STAGE(cur ^ 1, kbase + (kt + 1) * 64);

#pragma unroll
    for (int s = 0; s < 2; ++s) {
      bf16x8 af[MI], bfv[NI];
#pragma unroll
      for (int i = 0; i < MI; ++i) {
        const int r = wr + i * 16 + r16;
        af[i] = *reinterpret_cast<const bf16x8*>(
            &As[cur][r * 64 + (((s * 4 + kg) ^ (r & 7)) << 3)]);
      }
#pragma unroll
      for (int j = 0; j < NI; ++j) {
        const int r = wc + j * 16 + r16;
        bfv[j] = *reinterpret_cast<const bf16x8*>(
            &Bs[cur][r * 64 + (((s * 4 + kg) ^ (r & 7)) << 3)]);
      }
      __builtin_amdgcn_s_setprio(1);
#pragma unroll
      for (int i = 0; i < MI; ++i)
#pragma unroll
        for (int j = 0; j < NI; ++j)
          acc[i][j] = __builtin_amdgcn_mfma_f32_16x16x32_bf16(af[i], bfv[j], acc[i][j], 0, 0, 0);
      __builtin_amdgcn_s_setprio(0);
    }
    __syncthreads();
  }

  const int rg = (lane >> 4) * 4;
  const bool doVT = VT && (n0 >= 1024);
#pragma unroll
  for (int i = 0; i < MI; ++i) {
#pragma unroll
    for (int j = 0; j < NI; ++j) {
      int col = n0 + wc + j * 16 + r16;
      float bv = (bias && blockIdx.z == 0) ? bias[col] : 0.f;
#pragma unroll
      for (int r = 0; r < 4; ++r) {
        int row = m0 + wr + i * 16 + rg + r;
        float v = acc[i][j][r] * scale + bv;
        if (outF) {
          long idx = (long)row * ldof + col;
          if (accF) atomicAdd(&outF[idx], v);
          else outF[idx] = v;
        }
        if (outBf) {
          if (relu && v < 0.f) v = 0.f;
          u16 hv = f2bf(v);
          outBf[(long)row * ldob + col] = hv;
          if (doVT) Ts[wc + j * 16 + r16][wr + i * 16 + rg + r] = hv;
        }
      }
    }
  }

  if constexpr (VT) {
    if (doVT) {
      __syncthreads();
      const int d0 = n0 - 1024;
      constexpr int CH = MI * 4;
      constexpr int TOT = NI * 32 * CH;
#pragma unroll
      for (int c = 0; c < TOT / 256; ++c) {
        int idx = tid * (TOT / 256) + c;
        int drow = idx / CH, off = (idx % CH) * 8;
        *reinterpret_cast<uint4*>(vtOut + (long)(d0 + drow) * 2048 + m0 + off) =
            *reinterpret_cast<const uint4*>(&Ts[drow][off]);
      }
    }
  }
}

// ------------------------------------------------------------------
// Flash attention, cooperative 4-wave blocks, no-max softmax.
// K double-buffered, V single-buffered. Grid (32,8,4). bf16 partials.
// ------------------------------------------------------------------
constexpr int AFP = 72;

__global__ __launch_bounds__(256, 4) void flash_attn_split(
    const u16* __restrict__ qkv, const u16* __restrict__ vT,
    u16* __restrict__ oPart, float* __restrict__ lPart) {
  __shared__ u16 Ks[2][64 * AFP];
  __shared__ u16 Vs[64 * AFP];
  __shared__ u16 Ps[4][16 * AFP];
  const int h = blockIdx.y;
  const int q0 = blockIdx.x * 64;
  const int split = blockIdx.z;
  const int tid = threadIdx.x;
  const int lane = tid & 63, wid = tid >> 6;
  const int r16 = lane & 15, kg8 = (lane >> 4) * 8;

  bf16x8 qa0, qa1;
  {
    union U { uint4 v; u16 hh[8]; } a, b;
    const u16* qrow = qkv + (long)(q0 + wid * 16 + r16) * 1536 + 64 * h;
    a.v = *reinterpret_cast<const uint4*>(qrow + kg8);
    b.v = *reinterpret_cast<const uint4*>(qrow + 32 + kg8);
#pragma unroll
    for (int i = 0; i < 8; ++i) {
      a.hh[i] = f2bf(bf2f(a.hh[i]) * 0.125f);
      b.hh[i] = f2bf(bf2f(b.hh[i]) * 0.125f);
    }
    qa0 = __builtin_bit_cast(bf16x8, a.v);
    qa1 = __builtin_bit_cast(bf16x8, b.v);
  }

  const int srow = tid >> 2;
  const int scol = (tid & 3) * 16;
  const u16* kgl = qkv + 512 + 64 * h + scol;
  const u16* vgl = vT + (long)(64 * h + srow) * 2048 + scol;

  uint4 kr0, kr1, vr0, vr1;
  auto LOAD = [&](int g) {
    const u16* kp = kgl + (long)(g * 64 + srow) * 1536;
    kr0 = *reinterpret_cast<const uint4*>(kp);
    kr1 = *reinterpret_cast<const uint4*>(kp + 8);
    const u16* vp = vgl + g * 64;
    vr0 = *reinterpret_cast<const uint4*>(vp);
    vr1 = *reinterpret_cast<const uint4*>(vp + 8);
  };
  auto STOREK = [&](int b) {
    *reinterpret_cast<uint4*>(&Ks[b][srow * AFP + scol]) = kr0;
    *reinterpret_cast<uint4*>(&Ks[b][srow * AFP + scol + 8]) = kr1;
  };
  auto STOREV = [&]() {
    *reinterpret_cast<uint4*>(&Vs[srow * AFP + scol]) = vr0;
    *reinterpret_cast<uint4*>(&Vs[srow * AFP + scol + 8]) = vr1;
  };

  f32x4 oacc[4];
#pragma unroll
  for (int j = 0; j < 4; ++j) oacc[j] = f32x4{0.f, 0.f, 0.f, 0.f};
  float lsum[4] = {0.f, 0.f, 0.f, 0.f};

  const int g0 = split * 8;
  LOAD(g0);
  STOREK(0);
  STOREV();
  __syncthreads();

  for (int t = 0; t < 8; ++t) {
    const int cur = t & 1;
    if (t < 7) LOAD(g0 + t + 1);

    f32x4 sacc[4];
#pragma unroll
    for (int j = 0; j < 4; ++j) sacc[j] = f32x4{0.f, 0.f, 0.f, 0.f};
    __builtin_amdgcn_s_setprio(1);
#pragma unroll
    for (int j = 0; j < 4; ++j) {
      bf16x8 b0 = *reinterpret_cast<const bf16x8*>(&Ks[cur][(j * 16 + r16) * AFP + kg8]);
      bf16x8 b1 = *reinterpret_cast<const bf16x8*>(&Ks[cur][(j * 16 + r16) * AFP + 32 + kg8]);
      sacc[j] = __builtin_amdgcn_mfma_f32_16x16x32_bf16(qa0, b0, sacc[j], 0, 0, 0);
      sacc[j] = __builtin_amdgcn_mfma_f32_16x16x32_bf16(qa1, b1, sacc[j], 0, 0, 0);
    }
    __builtin_amdgcn_s_setprio(0);

#pragma unroll
    for (int r = 0; r < 4; ++r) {
      float e0 = __expf(sacc[0][r]);
      float e1 = __expf(sacc[1][r]);
      float e2 = __expf(sacc[2][r]);
      float e3 = __expf(sacc[3][r]);
      lsum[r] += (e0 + e1) + (e2 + e3);
      int prow = (lane >> 4) * 4 + r;
      Ps[wid][prow * AFP + r16] = f2bf(e0);
      Ps[wid][prow * AFP + 16 + r16] = f2bf(e1);
      Ps[wid][prow * AFP + 32 + r16] = f2bf(e2);
      Ps[wid][prow * AFP + 48 + r16] = f2bf(e3);
    }

#pragma unroll
    for (int st = 0; st < 2; ++st) {
      bf16x8 pa = *reinterpret_cast<const bf16x8*>(&Ps[wid][r16 * AFP + st * 32 + kg8]);
      __builtin_amdgcn_s_setprio(1);
#pragma unroll
      for (int j = 0; j < 4; ++j) {
        bf16x8 bv = *reinterpret_cast<const bf16x8*>(&Vs[(j * 16 + r16) * AFP + st * 32 + kg8]);
        oacc[j] = __builtin_amdgcn_mfma_f32_16x16x32_bf16(pa, bv, oacc[j], 0, 0, 0);
      }
      __builtin_amdgcn_s_setprio(0);
    }

    if (t < 7) {
      STOREK(cur ^ 1);
      __syncthreads();
      STOREV();
      __syncthreads();
    }
  }

  const int rg = (lane >> 4) * 4;
#pragma unroll
  for (int r = 0; r < 4; ++r) {
    float ls = lsum[r];
#pragma unroll
    for (int o = 1; o < 16; o <<= 1) ls += __shfl_xor(ls, o);
    int row = q0 + wid * 16 + rg + r;
    if (r16 == 0) lPart[(long)(split * 8 + h) * 2048 + row] = ls;
#pragma unroll
    for (int j = 0; j < 4; ++j)
      oPart[(long)split * 2048 * 512 + (long)row * 512 + 64 * h + j * 16 + r16] =
          f2bf(oacc[j][r]);
  }
}

// ------------------------------------------------------------------
// Fused: combine KV-split bf16 partials -> attn bf16, AND x += fsmn(v).
// ------------------------------------------------------------------
__global__ __launch_bounds__(256) void attn_norm_fsmn(
    const u16* __restrict__ oPart, const float* __restrict__ lPart,
    u16* __restrict__ attn, float* __restrict__ x,
    const u16* __restrict__ qkv, const float* __restrict__ fw) {
  const int t = blockIdx.x;
  const int d = threadIdx.x * 2;
  const int h = d >> 6;
  float l = 0.f;
#pragma unroll
  for (int s = 0; s < 4; ++s) l += lPart[(long)(s * 8 + h) * 2048 + t];
  float ox = 0.f, oy = 0.f;
#pragma unroll
  for (int s = 0; s < 4; ++s) {
    const u32 v = *reinterpret_cast<const u32*>(
        oPart + (long)s * 2048 * 512 + (long)t * 512 + d);
    ox += bf2f((u16)v);
    oy += bf2f((u16)(v >> 16));
  }
  const float inv = 1.f / l;
  u16* out = attn + (long)t * 512 + d;
  out[0] = f2bf(ox * inv);
  out[1] = f2bf(oy * inv);

  const u16* v = qkv + 1024 + d;
  float s0 = bf2f(v[(long)t * 1536]);
  float s1 = bf2f(v[(long)t * 1536 + 1]);
#pragma unroll
  for (int j = 0; j < 11; ++j) {
    int ts = t + j - 5;
    if (ts >= 0 && ts < 2048) {
      float w0 = fw[d * 11 + j], w1 = fw[(d + 1) * 11 + j];
      s0 += w0 * bf2f(v[(long)ts * 1536]);
      s1 += w1 * bf2f(v[(long)ts * 1536 + 1]);
    }
  }
  x[(long)t * 512 + d] += s0;
  x[(long)t * 512 + d + 1] += s1;
}

// ------------------------------------------------------------------
// LayerNorm over D=512, one block per row.
// ------------------------------------------------------------------
__device__ __forceinline__ void block_reduce2(float& s, float& ss) {
#pragma unroll
  for (int o = 32; o; o >>= 1) {
    s += __shfl_xor(s, o);
    ss += __shfl_xor(ss, o);
  }
  __shared__ float sm[8];
  int wid = threadIdx.x >> 6;
  if ((threadIdx.x & 63) == 0) {
    sm[wid] = s;
    sm[wid + 4] = ss;
  }
  __syncthreads();
  s = sm[0] + sm[1] + sm[2] + sm[3];
  ss = sm[4] + sm[5] + sm[6] + sm[7];
}

template <int OUTBF>
__global__ __launch_bounds__(256) void layernorm_k(
    const float* __restrict__ xin, const float* __restrict__ g,
    const float* __restrict__ bta, void* __restrict__ out) {
  const int row = blockIdx.x, tid = threadIdx.x;
  const float2 v = *reinterpret_cast<const float2*>(xin + (long)row * 512 + tid * 2);
  float s = v.x + v.y, ss = v.x * v.x + v.y * v.y;
  block_reduce2(s, ss);
  const float mean = s * (1.f / 512.f);
  const float var = ss * (1.f / 512.f) - mean * mean;
  const float inv = rsqrtf(var + 1e-5f);
  const float2 gg = *reinterpret_cast<const float2*>(g + tid * 2);
  const float2 bb = *reinterpret_cast<const float2*>(bta + tid * 2);
  const float y0 = (v.x - mean) * inv * gg.x + bb.x;
  const float y1 = (v.y - mean) * inv * gg.y + bb.y;
  if (OUTBF) {
    u16* o = (u16*)out + (long)row * 512 + tid * 2;
    o[0] = f2bf(y0);
    o[1] = f2bf(y1);
  } else {
    *reinterpret_cast<float2*>((float*)out + (long)row * 512 + tid * 2) =
        make_float2(y0, y1);
  }
}

// ------------------------------------------------------------------

extern "C" void kernel_launch(void* const* d_in, const int* in_sizes, int n_in,
                              void* d_out, int out_size, void* d_ws, size_t ws_size,
                              hipStream_t stream) {
  const float* in_x = (const float*)d_in[0];
  const float* ln1_g = (const float*)d_in[1];
  const float* ln1_b = (const float*)d_in[2];
  const float* Wqkv = (const float*)d_in[3];
  const float* bqkv = (const float*)d_in[4];
  const float* fsmn_w = (const float*)d_in[5];
  const float* Wout = (const float*)d_in[6];
  const float* bout = (const float*)d_in[7];
  const float* ln2_g = (const float*)d_in[8];
  const float* ln2_b = (const float*)d_in[9];
  const float* W1 = (const float*)d_in[10];
  const float* b1 = (const float*)d_in[11];
  const float* W2 = (const float*)d_in[12];
  const float* b2 = (const float*)d_in[13];
  const float* after_g = (const float*)d_in[14];
  const float* after_b = (const float*)d_in[15];

  const int T = 2048, D = 512, F = 2048, L = 8;

  char* p = (char*)d_ws;
  auto alloc = [&](size_t bytes) {
    char* r = p;
    p += (bytes + 255) & ~size_t(255);
    return r;
  };
  u16* WqkvT = (u16*)alloc(8L * 1536 * 512 * 2);
  u16* WoutT = (u16*)alloc(8L * 512 * 512 * 2);
  u16* W1T = (u16*)alloc(8L * 2048 * 512 * 2);
  u16* W2T = (u16*)alloc(8L * 512 * 2048 * 2);
  float* x = (float*)alloc((long)T * D * 4);
  u16* x1 = (u16*)alloc((long)T * D * 2);
  u16* qkv = (u16*)alloc((long)T * 1536 * 2);
  u16* vT = (u16*)alloc((long)D * T * 2);
  u16* attn = (u16*)alloc((long)T * D * 2);
  u16* hb = (u16*)alloc((long)T * F * 2);
  u16* oPart = (u16*)alloc(4L * T * D * 2);
  float* lPart = (float*)alloc(4L * 8 * T * 4);

  // ---- pre-pass: residual stream + bf16 transposed weights (1 dispatch) ----
  hipMemcpyAsync(x, in_x, (long)T * D * 4, hipMemcpyDeviceToDevice, stream);
  transpose_all<<<dim3(768 * 8, 1, 1), 256, 0, stream>>>(
      Wqkv, WqkvT, Wout, WoutT, W1, W1T, W2, W2T);

  for (int l = 0; l < L; ++l) {
    layernorm_k<1><<<T, 256, 0, stream>>>(x, ln1_g + 512 * l, ln1_b + 512 * l, x1);
    // QKV GEMM + fused vT emit   (BN=64: 768 blocks)
    gemm_bt<2, 2, 1><<<dim3(24, 32, 1), 256, 0, stream>>>(
        x1, 512, WqkvT + (long)l * 1536 * 512, 512, bqkv + 1536 * l,
        qkv, 1536, (float*)nullptr, 0, 0, vT, T, 1536, 512, 1, 1.f, 0);
    // flash attention partials (KV-split 4)
    flash_attn_split<<<dim3(32, 8, 4), 256, 0, stream>>>(qkv, vT, oPart, lPart);
    // combine partials -> attn, and x += fsmn(v)
    attn_norm_fsmn<<<T, 256, 0, stream>>>(oPart, lPart, attn, x, qkv,
                                          fsmn_w + (long)l * 512 * 11);
    // x += attn @ Wout + bout   (BN=64, split-K=4: 1024 blocks)
    gemm_bt<2, 2, 0><<<dim3(8, 32, 4), 256, 0, stream>>>(
        attn, 512, WoutT + (long)l * 512 * 512, 512, bout + 512 * l,
        (u16*)nullptr, 0, x, 512, 1, (u16*)nullptr, T, 512, 512, 4, 1.f, 0);
    layernorm_k<1><<<T, 256, 0, stream>>>(x, ln2_g + 512 * l, ln2_b + 512 * l, x1);
    // hb = relu(x1 @ W1 + b1)   (BN=64: 1024 blocks)
    gemm_bt<2, 2, 0><<<dim3(32, 32, 1), 256, 0, stream>>>(
        x1, 512, W1T + (long)l * 2048 * 512, 512, b1 + 2048 * l,
        hb, 2048, (float*)nullptr, 0, 0, (u16*)nullptr, T, 2048, 512, 1, 1.f, 1);
    // x += hb @ W2 + b2   (BN=64, split-K=4: 1024 blocks)
    gemm_bt<2, 2, 0><<<dim3(8, 32, 4), 256, 0, stream>>>(
        hb, 2048, W2T + (long)l * 512 * 2048, 2048, b2 + 512 * l,
        (u16*)nullptr, 0, x, 512, 1, (u16*)nullptr, T, 512, 2048, 4, 1.f, 0);
  }
  layernorm_k<0><<<T, 256, 0, stream>>>(x, after_g, after_b, (float*)d_out);
}

// Round 19
// 837.998 us; speedup vs baseline: 1.0476x; 1.0005x over previous
//
#include <hip/hip_runtime.h>

using u16 = unsigned short;
using u32 = unsigned int;

typedef __bf16 bf16x8 __attribute__((ext_vector_type(8)));
typedef float f32x4 __attribute__((ext_vector_type(4)));

typedef __attribute__((address_space(3))) u32 as3_u32;
typedef __attribute__((address_space(1))) const u32 as1_u32;

__device__ __forceinline__ u16 f2bf(float f) {
  u32 u = __builtin_bit_cast(u32, f);
  u = u + 0x7FFFu + ((u >> 16) & 1u);  // round-to-nearest-even
  return (u16)(u >> 16);
}
__device__ __forceinline__ float bf2f(u16 h) {
  return __builtin_bit_cast(float, (u32)h << 16);
}

// async global->LDS, 16B per lane; LDS dest = wave-uniform base + lane*16
__device__ __forceinline__ void gload16(const u16* g, u16* l) {
  __builtin_amdgcn_global_load_lds((as1_u32*)g, (as3_u32*)l, 16, 0, 0);
}

// ------------------------------------------------------------------
// All-weights transpose + f32->bf16, single dispatch, vectorized.
// 64x64 tiles; float4 loads, LDS round-trip, uint4 coalesced writes.
// Pad 67 u16/row: rows stepping by 8 -> bank offset 12 (mod 32), so
// phase-2's 8-row gather spreads ~all 32 banks (~2-way = free) vs the
// 4-way conflict of pad 66 (row-step-8 -> offset 8 -> 16 banks).
// ------------------------------------------------------------------
__global__ __launch_bounds__(256) void transpose_all(
    const float* __restrict__ w0, u16* __restrict__ o0,   // Wqkv 512x1536
    const float* __restrict__ w1, u16* __restrict__ o1,   // Wout 512x512
    const float* __restrict__ w2, u16* __restrict__ o2,   // W1   512x2048
    const float* __restrict__ w3, u16* __restrict__ o3) { // W2  2048x512
  __shared__ u16 tile[64][67];
  int id = blockIdx.x;
  const int layer = id / 768;
  int r = id % 768;
  const float* in;
  u16* out;
  int R, C, bx;
  if (r < 192)       { in = w0; out = o0; R = 512;  C = 1536; bx = 24; }
  else if (r < 256)  { r -= 192; in = w1; out = o1; R = 512;  C = 512;  bx = 8;  }
  else if (r < 512)  { r -= 256; in = w2; out = o2; R = 512;  C = 2048; bx = 32; }
  else               { r -= 512; in = w3; out = o3; R = 2048; C = 512;  bx = 8;  }
  const long zofs = (long)layer * R * C;
  const int c0 = (r % bx) * 64, r0 = (r / bx) * 64;
  const int tid = threadIdx.x;

  // phase 1: 1024 float4 loads (coalesced), bf16 convert, LDS store
#pragma unroll
  for (int k = 0; k < 4; ++k) {
    int it = tid + k * 256;
    int row = it >> 4, c4 = (it & 15) * 4;
    float4 v = *reinterpret_cast<const float4*>(
        in + zofs + (long)(r0 + row) * C + c0 + c4);
    tile[row][c4 + 0] = f2bf(v.x);
    tile[row][c4 + 1] = f2bf(v.y);
    tile[row][c4 + 2] = f2bf(v.z);
    tile[row][c4 + 3] = f2bf(v.w);
  }
  __syncthreads();

  // phase 2: gather 8 rows per thread-item, pack uint4, coalesced store
#pragma unroll
  for (int k = 0; k < 2; ++k) {
    int it = tid + k * 256;
    int cc = it >> 3, r8 = (it & 7) * 8;
    u16 tmp[8];
#pragma unroll
    for (int e = 0; e < 8; ++e) tmp[e] = tile[r8 + e][cc];
    *reinterpret_cast<uint4*>(out + zofs + (long)(c0 + cc) * R + r0 + r8) =
        *reinterpret_cast<const uint4*>(tmp);
  }
}

// ------------------------------------------------------------------
// General bf16 GEMM, B transposed. 2-phase prefetch (dbuf LDS), BK=64,
// 4 waves, MI x NI frags of mfma 16x16x32. gload_lds w16 + XOR swizzle.
// VT=1: blocks with n0>=1024 also emit vT[n-1024][m] via LDS transpose.
// blockIdx.z = K-chunk (split-K, atomicAdd f32 path).
// ------------------------------------------------------------------
template <int MI, int NI, int VT>
__global__ __launch_bounds__(256) void gemm_bt(
    const u16* __restrict__ A, int lda,
    const u16* __restrict__ B, int ldb,
    const float* __restrict__ bias,
    u16* __restrict__ outBf, int ldob,
    float* __restrict__ outF, int ldof, int accF,
    u16* __restrict__ vtOut,
    int M, int N, int K, int kChunks, float scale, int relu) {
  __shared__ u16 As[2][MI * 32 * 64];
  __shared__ u16 Bs[2][NI * 32 * 64];
  __shared__ u16 Ts[VT ? NI * 32 : 1][72];
  const int m0 = blockIdx.y * (MI * 32), n0 = blockIdx.x * (NI * 32);
  const int tid = threadIdx.x, lane = tid & 63, wid = tid >> 6;
  const int wr = (wid >> 1) * (MI * 16), wc = (wid & 1) * (NI * 16);
  const int r16 = lane & 15, kg = lane >> 4;

  const int lrow = lane >> 3;
  const int lchunk = (lane & 7) ^ lrow;

  f32x4 acc[MI][NI];
#pragma unroll
  for (int i = 0; i < MI; ++i)
#pragma unroll
    for (int j = 0; j < NI; ++j) acc[i][j] = f32x4{0.f, 0.f, 0.f, 0.f};

  const int kcs = K / kChunks;
  const int kbase = kcs * blockIdx.z;
  const int nkt = kcs / 64;

  auto STAGE = [&](int b, int k0) {
#pragma unroll
    for (int i = 0; i < MI; ++i) {
      const int r = i * 32 + wid * 8 + lrow;
      gload16(A + (long)(m0 + r) * lda + k0 + lchunk * 8,
              &As[b][wid * 512 + i * 2048]);
    }
#pragma unroll
    for (int j = 0; j < NI; ++j) {
      const int r = j * 32 + wid * 8 + lrow;
      gload16(B + (long)(n0 + r) * ldb + k0 + lchunk * 8,
              &Bs[b][wid * 512 + j * 2048]);
    }
  };

  STAGE(0, kbase);
  __syncthreads();

  for (int kt = 0; kt < nkt; ++kt) {
    const int cur = kt & 1;
    if (kt + 1 < nkt) STAGE(cur ^ 1, kbase + (kt + 1) * 64);

#pragma unroll
    for (int s = 0; s < 2; ++s) {
      bf16x8 af[MI], bfv[NI];
#pragma unroll
      for (int i = 0; i < MI; ++i) {
        const int r = wr + i * 16 + r16;
        af[i] = *reinterpret_cast<const bf16x8*>(
            &As[cur][r * 64 + (((s * 4 + kg) ^ (r & 7)) << 3)]);
      }
#pragma unroll
      for (int j = 0; j < NI; ++j) {
        const int r = wc + j * 16 + r16;
        bfv[j] = *reinterpret_cast<const bf16x8*>(
            &Bs[cur][r * 64 + (((s * 4 + kg) ^ (r & 7)) << 3)]);
      }
      __builtin_amdgcn_s_setprio(1);
#pragma unroll
      for (int i = 0; i < MI; ++i)
#pragma unroll
        for (int j = 0; j < NI; ++j)
          acc[i][j] = __builtin_amdgcn_mfma_f32_16x16x32_bf16(af[i], bfv[j], acc[i][j], 0, 0, 0);
      __builtin_amdgcn_s_setprio(0);
    }
    __syncthreads();
  }

  const int rg = (lane >> 4) * 4;
  const bool doVT = VT && (n0 >= 1024);
#pragma unroll
  for (int i = 0; i < MI; ++i) {
#pragma unroll
    for (int j = 0; j < NI; ++j) {
      int col = n0 + wc + j * 16 + r16;
      float bv = (bias && blockIdx.z == 0) ? bias[col] : 0.f;
#pragma unroll
      for (int r = 0; r < 4; ++r) {
        int row = m0 + wr + i * 16 + rg + r;
        float v = acc[i][j][r] * scale + bv;
        if (outF) {
          long idx = (long)row * ldof + col;
          if (accF) atomicAdd(&outF[idx], v);
          else outF[idx] = v;
        }
        if (outBf) {
          if (relu && v < 0.f) v = 0.f;
          u16 hv = f2bf(v);
          outBf[(long)row * ldob + col] = hv;
          if (doVT) Ts[wc + j * 16 + r16][wr + i * 16 + rg + r] = hv;
        }
      }
    }
  }

  if constexpr (VT) {
    if (doVT) {
      __syncthreads();
      const int d0 = n0 - 1024;
      constexpr int CH = MI * 4;
      constexpr int TOT = NI * 32 * CH;
#pragma unroll
      for (int c = 0; c < TOT / 256; ++c) {
        int idx = tid * (TOT / 256) + c;
        int drow = idx / CH, off = (idx % CH) * 8;
        *reinterpret_cast<uint4*>(vtOut + (long)(d0 + drow) * 2048 + m0 + off) =
            *reinterpret_cast<const uint4*>(&Ts[drow][off]);
      }
    }
  }
}

// ------------------------------------------------------------------
// Flash attention, cooperative 4-wave blocks, no-max softmax.
// K double-buffered, V single-buffered. Grid (32,8,4). bf16 partials.
// ------------------------------------------------------------------
constexpr int AFP = 72;

__global__ __launch_bounds__(256, 4) void flash_attn_split(
    const u16* __restrict__ qkv, const u16* __restrict__ vT,
    u16* __restrict__ oPart, float* __restrict__ lPart) {
  __shared__ u16 Ks[2][64 * AFP];
  __shared__ u16 Vs[64 * AFP];
  __shared__ u16 Ps[4][16 * AFP];
  const int h = blockIdx.y;
  const int q0 = blockIdx.x * 64;
  const int split = blockIdx.z;
  const int tid = threadIdx.x;
  const int lane = tid & 63, wid = tid >> 6;
  const int r16 = lane & 15, kg8 = (lane >> 4) * 8;

  bf16x8 qa0, qa1;
  {
    union U { uint4 v; u16 hh[8]; } a, b;
    const u16* qrow = qkv + (long)(q0 + wid * 16 + r16) * 1536 + 64 * h;
    a.v = *reinterpret_cast<const uint4*>(qrow + kg8);
    b.v = *reinterpret_cast<const uint4*>(qrow + 32 + kg8);
#pragma unroll
    for (int i = 0; i < 8; ++i) {
      a.hh[i] = f2bf(bf2f(a.hh[i]) * 0.125f);
      b.hh[i] = f2bf(bf2f(b.hh[i]) * 0.125f);
    }
    qa0 = __builtin_bit_cast(bf16x8, a.v);
    qa1 = __builtin_bit_cast(bf16x8, b.v);
  }

  const int srow = tid >> 2;
  const int scol = (tid & 3) * 16;
  const u16* kgl = qkv + 512 + 64 * h + scol;
  const u16* vgl = vT + (long)(64 * h + srow) * 2048 + scol;

  uint4 kr0, kr1, vr0, vr1;
  auto LOAD = [&](int g) {
    const u16* kp = kgl + (long)(g * 64 + srow) * 1536;
    kr0 = *reinterpret_cast<const uint4*>(kp);
    kr1 = *reinterpret_cast<const uint4*>(kp + 8);
    const u16* vp = vgl + g * 64;
    vr0 = *reinterpret_cast<const uint4*>(vp);
    vr1 = *reinterpret_cast<const uint4*>(vp + 8);
  };
  auto STOREK = [&](int b) {
    *reinterpret_cast<uint4*>(&Ks[b][srow * AFP + scol]) = kr0;
    *reinterpret_cast<uint4*>(&Ks[b][srow * AFP + scol + 8]) = kr1;
  };
  auto STOREV = [&]() {
    *reinterpret_cast<uint4*>(&Vs[srow * AFP + scol]) = vr0;
    *reinterpret_cast<uint4*>(&Vs[srow * AFP + scol + 8]) = vr1;
  };

  f32x4 oacc[4];
#pragma unroll
  for (int j = 0; j < 4; ++j) oacc[j] = f32x4{0.f, 0.f, 0.f, 0.f};
  float lsum[4] = {0.f, 0.f, 0.f, 0.f};

  const int g0 = split * 8;
  LOAD(g0);
  STOREK(0);
  STOREV();
  __syncthreads();

  for (int t = 0; t < 8; ++t) {
    const int cur = t & 1;
    if (t < 7) LOAD(g0 + t + 1);

    f32x4 sacc[4];
#pragma unroll
    for (int j = 0; j < 4; ++j) sacc[j] = f32x4{0.f, 0.f, 0.f, 0.f};
    __builtin_amdgcn_s_setprio(1);
#pragma unroll
    for (int j = 0; j < 4; ++j) {
      bf16x8 b0 = *reinterpret_cast<const bf16x8*>(&Ks[cur][(j * 16 + r16) * AFP + kg8]);
      bf16x8 b1 = *reinterpret_cast<const bf16x8*>(&Ks[cur][(j * 16 + r16) * AFP + 32 + kg8]);
      sacc[j] = __builtin_amdgcn_mfma_f32_16x16x32_bf16(qa0, b0, sacc[j], 0, 0, 0);
      sacc[j] = __builtin_amdgcn_mfma_f32_16x16x32_bf16(qa1, b1, sacc[j], 0, 0, 0);
    }
    __builtin_amdgcn_s_setprio(0);

#pragma unroll
    for (int r = 0; r < 4; ++r) {
      float e0 = __expf(sacc[0][r]);
      float e1 = __expf(sacc[1][r]);
      float e2 = __expf(sacc[2][r]);
      float e3 = __expf(sacc[3][r]);
      lsum[r] += (e0 + e1) + (e2 + e3);
      int prow = (lane >> 4) * 4 + r;
      Ps[wid][prow * AFP + r16] = f2bf(e0);
      Ps[wid][prow * AFP + 16 + r16] = f2bf(e1);
      Ps[wid][prow * AFP + 32 + r16] = f2bf(e2);
      Ps[wid][prow * AFP + 48 + r16] = f2bf(e3);
    }

#pragma unroll
    for (int st = 0; st < 2; ++st) {
      bf16x8 pa = *reinterpret_cast<const bf16x8*>(&Ps[wid][r16 * AFP + st * 32 + kg8]);
      __builtin_amdgcn_s_setprio(1);
#pragma unroll
      for (int j = 0; j < 4; ++j) {
        bf16x8 bv = *reinterpret_cast<const bf16x8*>(&Vs[(j * 16 + r16) * AFP + st * 32 + kg8]);
        oacc[j] = __builtin_amdgcn_mfma_f32_16x16x32_bf16(pa, bv, oacc[j], 0, 0, 0);
      }
      __builtin_amdgcn_s_setprio(0);
    }

    if (t < 7) {
      STOREK(cur ^ 1);
      __syncthreads();
      STOREV();
      __syncthreads();
    }
  }

  const int rg = (lane >> 4) * 4;
#pragma unroll
  for (int r = 0; r < 4; ++r) {
    float ls = lsum[r];
#pragma unroll
    for (int o = 1; o < 16; o <<= 1) ls += __shfl_xor(ls, o);
    int row = q0 + wid * 16 + rg + r;
    if (r16 == 0) lPart[(long)(split * 8 + h) * 2048 + row] = ls;
#pragma unroll
    for (int j = 0; j < 4; ++j)
      oPart[(long)split * 2048 * 512 + (long)row * 512 + 64 * h + j * 16 + r16] =
          f2bf(oacc[j][r]);
  }
}

// ------------------------------------------------------------------
// Fused: combine KV-split bf16 partials -> attn bf16, AND x += fsmn(v).
// ------------------------------------------------------------------
__global__ __launch_bounds__(256) void attn_norm_fsmn(
    const u16* __restrict__ oPart, const float* __restrict__ lPart,
    u16* __restrict__ attn, float* __restrict__ x,
    const u16* __restrict__ qkv, const float* __restrict__ fw) {
  const int t = blockIdx.x;
  const int d = threadIdx.x * 2;
  const int h = d >> 6;
  float l = 0.f;
#pragma unroll
  for (int s = 0; s < 4; ++s) l += lPart[(long)(s * 8 + h) * 2048 + t];
  float ox = 0.f, oy = 0.f;
#pragma unroll
  for (int s = 0; s < 4; ++s) {
    const u32 v = *reinterpret_cast<const u32*>(
        oPart + (long)s * 2048 * 512 + (long)t * 512 + d);
    ox += bf2f((u16)v);
    oy += bf2f((u16)(v >> 16));
  }
  const float inv = 1.f / l;
  u16* out = attn + (long)t * 512 + d;
  out[0] = f2bf(ox * inv);
  out[1] = f2bf(oy * inv);

  const u16* v = qkv + 1024 + d;
  float s0 = bf2f(v[(long)t * 1536]);
  float s1 = bf2f(v[(long)t * 1536 + 1]);
#pragma unroll
  for (int j = 0; j < 11; ++j) {
    int ts = t + j - 5;
    if (ts >= 0 && ts < 2048) {
      float w0 = fw[d * 11 + j], w1 = fw[(d + 1) * 11 + j];
      s0 += w0 * bf2f(v[(long)ts * 1536]);
      s1 += w1 * bf2f(v[(long)ts * 1536 + 1]);
    }
  }
  x[(long)t * 512 + d] += s0;
  x[(long)t * 512 + d + 1] += s1;
}

// ------------------------------------------------------------------
// LayerNorm over D=512, one block per row.
// ------------------------------------------------------------------
__device__ __forceinline__ void block_reduce2(float& s, float& ss) {
#pragma unroll
  for (int o = 32; o; o >>= 1) {
    s += __shfl_xor(s, o);
    ss += __shfl_xor(ss, o);
  }
  __shared__ float sm[8];
  int wid = threadIdx.x >> 6;
  if ((threadIdx.x & 63) == 0) {
    sm[wid] = s;
    sm[wid + 4] = ss;
  }
  __syncthreads();
  s = sm[0] + sm[1] + sm[2] + sm[3];
  ss = sm[4] + sm[5] + sm[6] + sm[7];
}

template <int OUTBF>
__global__ __launch_bounds__(256) void layernorm_k(
    const float* __restrict__ xin, const float* __restrict__ g,
    const float* __restrict__ bta, void* __restrict__ out) {
  const int row = blockIdx.x, tid = threadIdx.x;
  const float2 v = *reinterpret_cast<const float2*>(xin + (long)row * 512 + tid * 2);
  float s = v.x + v.y, ss = v.x * v.x + v.y * v.y;
  block_reduce2(s, ss);
  const float mean = s * (1.f / 512.f);
  const float var = ss * (1.f / 512.f) - mean * mean;
  const float inv = rsqrtf(var + 1e-5f);
  const float2 gg = *reinterpret_cast<const float2*>(g + tid * 2);
  const float2 bb = *reinterpret_cast<const float2*>(bta + tid * 2);
  const float y0 = (v.x - mean) * inv * gg.x + bb.x;
  const float y1 = (v.y - mean) * inv * gg.y + bb.y;
  if (OUTBF) {
    u16* o = (u16*)out + (long)row * 512 + tid * 2;
    o[0] = f2bf(y0);
    o[1] = f2bf(y1);
  } else {
    *reinterpret_cast<float2*>((float*)out + (long)row * 512 + tid * 2) =
        make_float2(y0, y1);
  }
}

// ------------------------------------------------------------------

extern "C" void kernel_launch(void* const* d_in, const int* in_sizes, int n_in,
                              void* d_out, int out_size, void* d_ws, size_t ws_size,
                              hipStream_t stream) {
  const float* in_x = (const float*)d_in[0];
  const float* ln1_g = (const float*)d_in[1];
  const float* ln1_b = (const float*)d_in[2];
  const float* Wqkv = (const float*)d_in[3];
  const float* bqkv = (const float*)d_in[4];
  const float* fsmn_w = (const float*)d_in[5];
  const float* Wout = (const float*)d_in[6];
  const float* bout = (const float*)d_in[7];
  const float* ln2_g = (const float*)d_in[8];
  const float* ln2_b = (const float*)d_in[9];
  const float* W1 = (const float*)d_in[10];
  const float* b1 = (const float*)d_in[11];
  const float* W2 = (const float*)d_in[12];
  const float* b2 = (const float*)d_in[13];
  const float* after_g = (const float*)d_in[14];
  const float* after_b = (const float*)d_in[15];

  const int T = 2048, D = 512, F = 2048, L = 8;

  char* p = (char*)d_ws;
  auto alloc = [&](size_t bytes) {
    char* r = p;
    p += (bytes + 255) & ~size_t(255);
    return r;
  };
  u16* WqkvT = (u16*)alloc(8L * 1536 * 512 * 2);
  u16* WoutT = (u16*)alloc(8L * 512 * 512 * 2);
  u16* W1T = (u16*)alloc(8L * 2048 * 512 * 2);
  u16* W2T = (u16*)alloc(8L * 512 * 2048 * 2);
  float* x = (float*)alloc((long)T * D * 4);
  u16* x1 = (u16*)alloc((long)T * D * 2);
  u16* qkv = (u16*)alloc((long)T * 1536 * 2);
  u16* vT = (u16*)alloc((long)D * T * 2);
  u16* attn = (u16*)alloc((long)T * D * 2);
  u16* hb = (u16*)alloc((long)T * F * 2);
  u16* oPart = (u16*)alloc(4L * T * D * 2);
  float* lPart = (float*)alloc(4L * 8 * T * 4);

  // ---- pre-pass: residual stream + bf16 transposed weights (1 dispatch) ----
  hipMemcpyAsync(x, in_x, (long)T * D * 4, hipMemcpyDeviceToDevice, stream);
  transpose_all<<<dim3(768 * 8, 1, 1), 256, 0, stream>>>(
      Wqkv, WqkvT, Wout, WoutT, W1, W1T, W2, W2T);

  for (int l = 0; l < L; ++l) {
    layernorm_k<1><<<T, 256, 0, stream>>>(x, ln1_g + 512 * l, ln1_b + 512 * l, x1);
    // QKV GEMM + fused vT emit   (BN=64: 768 blocks)
    gemm_bt<2, 2, 1><<<dim3(24, 32, 1), 256, 0, stream>>>(
        x1, 512, WqkvT + (long)l * 1536 * 512, 512, bqkv + 1536 * l,
        qkv, 1536, (float*)nullptr, 0, 0, vT, T, 1536, 512, 1, 1.f, 0);
    // flash attention partials (KV-split 4)
    flash_attn_split<<<dim3(32, 8, 4), 256, 0, stream>>>(qkv, vT, oPart, lPart);
    // combine partials -> attn, and x += fsmn(v)
    attn_norm_fsmn<<<T, 256, 0, stream>>>(oPart, lPart, attn, x, qkv,
                                          fsmn_w + (long)l * 512 * 11);
    // x += attn @ Wout + bout   (BN=64, split-K=4: 1024 blocks)
    gemm_bt<2, 2, 0><<<dim3(8, 32, 4), 256, 0, stream>>>(
        attn, 512, WoutT + (long)l * 512 * 512, 512, bout + 512 * l,
        (u16*)nullptr, 0, x, 512, 1, (u16*)nullptr, T, 512, 512, 4, 1.f, 0);
    layernorm_k<1><<<T, 256, 0, stream>>>(x, ln2_g + 512 * l, ln2_b + 512 * l, x1);
    // hb = relu(x1 @ W1 + b1)   (BN=64: 1024 blocks)
    gemm_bt<2, 2, 0><<<dim3(32, 32, 1), 256, 0, stream>>>(
        x1, 512, W1T + (long)l * 2048 * 512, 512, b1 + 2048 * l,
        hb, 2048, (float*)nullptr, 0, 0, (u16*)nullptr, T, 2048, 512, 1, 1.f, 1);
    // x += hb @ W2 + b2   (BN=64, split-K=4: 1024 blocks)
    gemm_bt<2, 2, 0><<<dim3(8, 32, 4), 256, 0, stream>>>(
        hb, 2048, W2T + (long)l * 512 * 2048, 2048, b2 + 512 * l,
        (u16*)nullptr, 0, x, 512, 1, (u16*)nullptr, T, 512, 2048, 4, 1.f, 0);
  }
  layernorm_k<0><<<T, 256, 0, stream>>>(x, after_g, after_b, (float*)d_out);
}

// Round 20
// 830.340 us; speedup vs baseline: 1.0572x; 1.0092x over previous
//
#include <hip/hip_runtime.h>

using u16 = unsigned short;
using u32 = unsigned int;

typedef __bf16 bf16x8 __attribute__((ext_vector_type(8)));
typedef float f32x4 __attribute__((ext_vector_type(4)));

typedef __attribute__((address_space(3))) u32 as3_u32;
typedef __attribute__((address_space(1))) const u32 as1_u32;

__device__ __forceinline__ u16 f2bf(float f) {
  u32 u = __builtin_bit_cast(u32, f);
  u = u + 0x7FFFu + ((u >> 16) & 1u);  // round-to-nearest-even
  return (u16)(u >> 16);
}
__device__ __forceinline__ float bf2f(u16 h) {
  return __builtin_bit_cast(float, (u32)h << 16);
}

// async global->LDS, 16B per lane; LDS dest = wave-uniform base + lane*16
__device__ __forceinline__ void gload16(const u16* g, u16* l) {
  __builtin_amdgcn_global_load_lds((as1_u32*)g, (as3_u32*)l, 16, 0, 0);
}

// ------------------------------------------------------------------
// All-weights transpose + f32->bf16, single dispatch, 2 tiles/block
// for memory-pipeline depth (8 float4 loads in flight per thread).
// Pad 67 (bank-conflict-free, verified r19). Grid 384 pairs x 8 layers.
// ------------------------------------------------------------------
__global__ __launch_bounds__(256) void transpose_all(
    const float* __restrict__ w0, u16* __restrict__ o0,   // Wqkv 512x1536
    const float* __restrict__ w1, u16* __restrict__ o1,   // Wout 512x512
    const float* __restrict__ w2, u16* __restrict__ o2,   // W1   512x2048
    const float* __restrict__ w3, u16* __restrict__ o3) { // W2  2048x512
  __shared__ u16 tile[2][64][67];
  int id = blockIdx.x;
  const int layer = id / 384;
  int r = id % 384;
  const float* in;
  u16* out;
  int R, C, bx;
  if (r < 96)        { in = w0; out = o0; R = 512;  C = 1536; bx = 24; }
  else if (r < 128)  { r -= 96;  in = w1; out = o1; R = 512;  C = 512;  bx = 8;  }
  else if (r < 256)  { r -= 128; in = w2; out = o2; R = 512;  C = 2048; bx = 32; }
  else               { r -= 256; in = w3; out = o3; R = 2048; C = 512;  bx = 8;  }
  const long zofs = (long)layer * R * C;
  const int tid = threadIdx.x;
  int c0[2], r0[2];
#pragma unroll
  for (int p = 0; p < 2; ++p) {
    int t = r * 2 + p;
    c0[p] = (t % bx) * 64;
    r0[p] = (t / bx) * 64;
  }

  // phase 1: 2x4 float4 loads per thread (both tiles in flight), convert
#pragma unroll
  for (int k = 0; k < 4; ++k) {
    int it = tid + k * 256;
    int row = it >> 4, c4 = (it & 15) * 4;
#pragma unroll
    for (int p = 0; p < 2; ++p) {
      float4 v = *reinterpret_cast<const float4*>(
          in + zofs + (long)(r0[p] + row) * C + c0[p] + c4);
      tile[p][row][c4 + 0] = f2bf(v.x);
      tile[p][row][c4 + 1] = f2bf(v.y);
      tile[p][row][c4 + 2] = f2bf(v.z);
      tile[p][row][c4 + 3] = f2bf(v.w);
    }
  }
  __syncthreads();

  // phase 2: gather 8 rows, pack uint4, coalesced store (both tiles)
#pragma unroll
  for (int k = 0; k < 2; ++k) {
    int it = tid + k * 256;
    int cc = it >> 3, r8 = (it & 7) * 8;
#pragma unroll
    for (int p = 0; p < 2; ++p) {
      u16 tmp[8];
#pragma unroll
      for (int e = 0; e < 8; ++e) tmp[e] = tile[p][r8 + e][cc];
      *reinterpret_cast<uint4*>(out + zofs + (long)(c0[p] + cc) * R + r0[p] + r8) =
          *reinterpret_cast<const uint4*>(tmp);
    }
  }
}

// ------------------------------------------------------------------
// General bf16 GEMM, B transposed. 2-phase prefetch (dbuf LDS), BK=64,
// 4 waves, MI x NI frags of mfma 16x16x32. gload_lds w16 + XOR swizzle.
// VT=1: blocks with n0>=1024 also emit vT[n-1024][m] via LDS transpose.
// blockIdx.z = K-chunk (split-K, atomicAdd f32 path).
// ------------------------------------------------------------------
template <int MI, int NI, int VT>
__global__ __launch_bounds__(256) void gemm_bt(
    const u16* __restrict__ A, int lda,
    const u16* __restrict__ B, int ldb,
    const float* __restrict__ bias,
    u16* __restrict__ outBf, int ldob,
    float* __restrict__ outF, int ldof, int accF,
    u16* __restrict__ vtOut,
    int M, int N, int K, int kChunks, float scale, int relu) {
  __shared__ u16 As[2][MI * 32 * 64];
  __shared__ u16 Bs[2][NI * 32 * 64];
  __shared__ u16 Ts[VT ? NI * 32 : 1][72];
  const int m0 = blockIdx.y * (MI * 32), n0 = blockIdx.x * (NI * 32);
  const int tid = threadIdx.x, lane = tid & 63, wid = tid >> 6;
  const int wr = (wid >> 1) * (MI * 16), wc = (wid & 1) * (NI * 16);
  const int r16 = lane & 15, kg = lane >> 4;

  const int lrow = lane >> 3;
  const int lchunk = (lane & 7) ^ lrow;

  f32x4 acc[MI][NI];
#pragma unroll
  for (int i = 0; i < MI; ++i)
#pragma unroll
    for (int j = 0; j < NI; ++j) acc[i][j] = f32x4{0.f, 0.f, 0.f, 0.f};

  const int kcs = K / kChunks;
  const int kbase = kcs * blockIdx.z;
  const int nkt = kcs / 64;

  auto STAGE = [&](int b, int k0) {
#pragma unroll
    for (int i = 0; i < MI; ++i) {
      const int r = i * 32 + wid * 8 + lrow;
      gload16(A + (long)(m0 + r) * lda + k0 + lchunk * 8,
              &As[b][wid * 512 + i * 2048]);
    }
#pragma unroll
    for (int j = 0; j < NI; ++j) {
      const int r = j * 32 + wid * 8 + lrow;
      gload16(B + (long)(n0 + r) * ldb + k0 + lchunk * 8,
              &Bs[b][wid * 512 + j * 2048]);
    }
  };

  STAGE(0, kbase);
  __syncthreads();

  for (int kt = 0; kt < nkt; ++kt) {
    const int cur = kt & 1;
    if (kt + 1 < nkt) STAGE(cur ^ 1, kbase + (kt + 1) * 64);

#pragma unroll
    for (int s = 0; s < 2; ++s) {
      bf16x8 af[MI], bfv[NI];
#pragma unroll
      for (int i = 0; i < MI; ++i) {
        const int r = wr + i * 16 + r16;
        af[i] = *reinterpret_cast<const bf16x8*>(
            &As[cur][r * 64 + (((s * 4 + kg) ^ (r & 7)) << 3)]);
      }
#pragma unroll
      for (int j = 0; j < NI; ++j) {
        const int r = wc + j * 16 + r16;
        bfv[j] = *reinterpret_cast<const bf16x8*>(
            &Bs[cur][r * 64 + (((s * 4 + kg) ^ (r & 7)) << 3)]);
      }
      __builtin_amdgcn_s_setprio(1);
#pragma unroll
      for (int i = 0; i < MI; ++i)
#pragma unroll
        for (int j = 0; j < NI; ++j)
          acc[i][j] = __builtin_amdgcn_mfma_f32_16x16x32_bf16(af[i], bfv[j], acc[i][j], 0, 0, 0);
      __builtin_amdgcn_s_setprio(0);
    }
    __syncthreads();
  }

  const int rg = (lane >> 4) * 4;
  const bool doVT = VT && (n0 >= 1024);
#pragma unroll
  for (int i = 0; i < MI; ++i) {
#pragma unroll
    for (int j = 0; j < NI; ++j) {
      int col = n0 + wc + j * 16 + r16;
      float bv = (bias && blockIdx.z == 0) ? bias[col] : 0.f;
#pragma unroll
      for (int r = 0; r < 4; ++r) {
        int row = m0 + wr + i * 16 + rg + r;
        float v = acc[i][j][r] * scale + bv;
        if (outF) {
          long idx = (long)row * ldof + col;
          if (accF) atomicAdd(&outF[idx], v);
          else outF[idx] = v;
        }
        if (outBf) {
          if (relu && v < 0.f) v = 0.f;
          u16 hv = f2bf(v);
          outBf[(long)row * ldob + col] = hv;
          if (doVT) Ts[wc + j * 16 + r16][wr + i * 16 + rg + r] = hv;
        }
      }
    }
  }

  if constexpr (VT) {
    if (doVT) {
      __syncthreads();
      const int d0 = n0 - 1024;
      constexpr int CH = MI * 4;
      constexpr int TOT = NI * 32 * CH;
#pragma unroll
      for (int c = 0; c < TOT / 256; ++c) {
        int idx = tid * (TOT / 256) + c;
        int drow = idx / CH, off = (idx % CH) * 8;
        *reinterpret_cast<uint4*>(vtOut + (long)(d0 + drow) * 2048 + m0 + off) =
            *reinterpret_cast<const uint4*>(&Ts[drow][off]);
      }
    }
  }
}

// ------------------------------------------------------------------
// Flash attention, cooperative 4-wave blocks, no-max softmax.
// K double-buffered, V single-buffered. Grid (32,8,4). bf16 partials.
// ------------------------------------------------------------------
constexpr int AFP = 72;

__global__ __launch_bounds__(256, 4) void flash_attn_split(
    const u16* __restrict__ qkv, const u16* __restrict__ vT,
    u16* __restrict__ oPart, float* __restrict__ lPart) {
  __shared__ u16 Ks[2][64 * AFP];
  __shared__ u16 Vs[64 * AFP];
  __shared__ u16 Ps[4][16 * AFP];
  const int h = blockIdx.y;
  const int q0 = blockIdx.x * 64;
  const int split = blockIdx.z;
  const int tid = threadIdx.x;
  const int lane = tid & 63, wid = tid >> 6;
  const int r16 = lane & 15, kg8 = (lane >> 4) * 8;

  bf16x8 qa0, qa1;
  {
    union U { uint4 v; u16 hh[8]; } a, b;
    const u16* qrow = qkv + (long)(q0 + wid * 16 + r16) * 1536 + 64 * h;
    a.v = *reinterpret_cast<const uint4*>(qrow + kg8);
    b.v = *reinterpret_cast<const uint4*>(qrow + 32 + kg8);
#pragma unroll
    for (int i = 0; i < 8; ++i) {
      a.hh[i] = f2bf(bf2f(a.hh[i]) * 0.125f);
      b.hh[i] = f2bf(bf2f(b.hh[i]) * 0.125f);
    }
    qa0 = __builtin_bit_cast(bf16x8, a.v);
    qa1 = __builtin_bit_cast(bf16x8, b.v);
  }

  const int srow = tid >> 2;
  const int scol = (tid & 3) * 16;
  const u16* kgl = qkv + 512 + 64 * h + scol;
  const u16* vgl = vT + (long)(64 * h + srow) * 2048 + scol;

  uint4 kr0, kr1, vr0, vr1;
  auto LOAD = [&](int g) {
    const u16* kp = kgl + (long)(g * 64 + srow) * 1536;
    kr0 = *reinterpret_cast<const uint4*>(kp);
    kr1 = *reinterpret_cast<const uint4*>(kp + 8);
    const u16* vp = vgl + g * 64;
    vr0 = *reinterpret_cast<const uint4*>(vp);
    vr1 = *reinterpret_cast<const uint4*>(vp + 8);
  };
  auto STOREK = [&](int b) {
    *reinterpret_cast<uint4*>(&Ks[b][srow * AFP + scol]) = kr0;
    *reinterpret_cast<uint4*>(&Ks[b][srow * AFP + scol + 8]) = kr1;
  };
  auto STOREV = [&]() {
    *reinterpret_cast<uint4*>(&Vs[srow * AFP + scol]) = vr0;
    *reinterpret_cast<uint4*>(&Vs[srow * AFP + scol + 8]) = vr1;
  };

  f32x4 oacc[4];
#pragma unroll
  for (int j = 0; j < 4; ++j) oacc[j] = f32x4{0.f, 0.f, 0.f, 0.f};
  float lsum[4] = {0.f, 0.f, 0.f, 0.f};

  const int g0 = split * 8;
  LOAD(g0);
  STOREK(0);
  STOREV();
  __syncthreads();

  for (int t = 0; t < 8; ++t) {
    const int cur = t & 1;
    if (t < 7) LOAD(g0 + t + 1);

    f32x4 sacc[4];
#pragma unroll
    for (int j = 0; j < 4; ++j) sacc[j] = f32x4{0.f, 0.f, 0.f, 0.f};
    __builtin_amdgcn_s_setprio(1);
#pragma unroll
    for (int j = 0; j < 4; ++j) {
      bf16x8 b0 = *reinterpret_cast<const bf16x8*>(&Ks[cur][(j * 16 + r16) * AFP + kg8]);
      bf16x8 b1 = *reinterpret_cast<const bf16x8*>(&Ks[cur][(j * 16 + r16) * AFP + 32 + kg8]);
      sacc[j] = __builtin_amdgcn_mfma_f32_16x16x32_bf16(qa0, b0, sacc[j], 0, 0, 0);
      sacc[j] = __builtin_amdgcn_mfma_f32_16x16x32_bf16(qa1, b1, sacc[j], 0, 0, 0);
    }
    __builtin_amdgcn_s_setprio(0);

#pragma unroll
    for (int r = 0; r < 4; ++r) {
      float e0 = __expf(sacc[0][r]);
      float e1 = __expf(sacc[1][r]);
      float e2 = __expf(sacc[2][r]);
      float e3 = __expf(sacc[3][r]);
      lsum[r] += (e0 + e1) + (e2 + e3);
      int prow = (lane >> 4) * 4 + r;
      Ps[wid][prow * AFP + r16] = f2bf(e0);
      Ps[wid][prow * AFP + 16 + r16] = f2bf(e1);
      Ps[wid][prow * AFP + 32 + r16] = f2bf(e2);
      Ps[wid][prow * AFP + 48 + r16] = f2bf(e3);
    }

#pragma unroll
    for (int st = 0; st < 2; ++st) {
      bf16x8 pa = *reinterpret_cast<const bf16x8*>(&Ps[wid][r16 * AFP + st * 32 + kg8]);
      __builtin_amdgcn_s_setprio(1);
#pragma unroll
      for (int j = 0; j < 4; ++j) {
        bf16x8 bv = *reinterpret_cast<const bf16x8*>(&Vs[(j * 16 + r16) * AFP + st * 32 + kg8]);
        oacc[j] = __builtin_amdgcn_mfma_f32_16x16x32_bf16(pa, bv, oacc[j], 0, 0, 0);
      }
      __builtin_amdgcn_s_setprio(0);
    }

    if (t < 7) {
      STOREK(cur ^ 1);
      __syncthreads();
      STOREV();
      __syncthreads();
    }
  }

  const int rg = (lane >> 4) * 4;
#pragma unroll
  for (int r = 0; r < 4; ++r) {
    float ls = lsum[r];
#pragma unroll
    for (int o = 1; o < 16; o <<= 1) ls += __shfl_xor(ls, o);
    int row = q0 + wid * 16 + rg + r;
    if (r16 == 0) lPart[(long)(split * 8 + h) * 2048 + row] = ls;
#pragma unroll
    for (int j = 0; j < 4; ++j)
      oPart[(long)split * 2048 * 512 + (long)row * 512 + 64 * h + j * 16 + r16] =
          f2bf(oacc[j][r]);
  }
}

// ------------------------------------------------------------------
// Fused: combine KV-split bf16 partials -> attn bf16, AND x += fsmn(v).
// ------------------------------------------------------------------
__global__ __launch_bounds__(256) void attn_norm_fsmn(
    const u16* __restrict__ oPart, const float* __restrict__ lPart,
    u16* __restrict__ attn, float* __restrict__ x,
    const u16* __restrict__ qkv, const float* __restrict__ fw) {
  const int t = blockIdx.x;
  const int d = threadIdx.x * 2;
  const int h = d >> 6;
  float l = 0.f;
#pragma unroll
  for (int s = 0; s < 4; ++s) l += lPart[(long)(s * 8 + h) * 2048 + t];
  float ox = 0.f, oy = 0.f;
#pragma unroll
  for (int s = 0; s < 4; ++s) {
    const u32 v = *reinterpret_cast<const u32*>(
        oPart + (long)s * 2048 * 512 + (long)t * 512 + d);
    ox += bf2f((u16)v);
    oy += bf2f((u16)(v >> 16));
  }
  const float inv = 1.f / l;
  u16* out = attn + (long)t * 512 + d;
  out[0] = f2bf(ox * inv);
  out[1] = f2bf(oy * inv);

  const u16* v = qkv + 1024 + d;
  float s0 = bf2f(v[(long)t * 1536]);
  float s1 = bf2f(v[(long)t * 1536 + 1]);
#pragma unroll
  for (int j = 0; j < 11; ++j) {
    int ts = t + j - 5;
    if (ts >= 0 && ts < 2048) {
      float w0 = fw[d * 11 + j], w1 = fw[(d + 1) * 11 + j];
      s0 += w0 * bf2f(v[(long)ts * 1536]);
      s1 += w1 * bf2f(v[(long)ts * 1536 + 1]);
    }
  }
  x[(long)t * 512 + d] += s0;
  x[(long)t * 512 + d + 1] += s1;
}

// ------------------------------------------------------------------
// LayerNorm, wave-per-row: 4 rows/block, 64 lanes x 8 elems, no LDS,
// no barriers (pure 6-step shuffle reduce).
// ------------------------------------------------------------------
template <int OUTBF>
__global__ __launch_bounds__(256) void layernorm_k(
    const float* __restrict__ xin, const float* __restrict__ g,
    const float* __restrict__ bta, void* __restrict__ out) {
  const int lane = threadIdx.x & 63;
  const int row = blockIdx.x * 4 + (threadIdx.x >> 6);
  const float* xr = xin + (long)row * 512 + lane * 8;
  const float4 v0 = *reinterpret_cast<const float4*>(xr);
  const float4 v1 = *reinterpret_cast<const float4*>(xr + 4);
  float s = ((v0.x + v0.y) + (v0.z + v0.w)) + ((v1.x + v1.y) + (v1.z + v1.w));
  float ss = ((v0.x * v0.x + v0.y * v0.y) + (v0.z * v0.z + v0.w * v0.w)) +
             ((v1.x * v1.x + v1.y * v1.y) + (v1.z * v1.z + v1.w * v1.w));
#pragma unroll
  for (int o = 32; o; o >>= 1) {
    s += __shfl_xor(s, o);
    ss += __shfl_xor(ss, o);
  }
  const float mean = s * (1.f / 512.f);
  const float var = ss * (1.f / 512.f) - mean * mean;
  const float inv = rsqrtf(var + 1e-5f);
  const float4 g0 = *reinterpret_cast<const float4*>(g + lane * 8);
  const float4 g1 = *reinterpret_cast<const float4*>(g + lane * 8 + 4);
  const float4 b0 = *reinterpret_cast<const float4*>(bta + lane * 8);
  const float4 b1 = *reinterpret_cast<const float4*>(bta + lane * 8 + 4);
  float y[8];
  y[0] = (v0.x - mean) * inv * g0.x + b0.x;
  y[1] = (v0.y - mean) * inv * g0.y + b0.y;
  y[2] = (v0.z - mean) * inv * g0.z + b0.z;
  y[3] = (v0.w - mean) * inv * g0.w + b0.w;
  y[4] = (v1.x - mean) * inv * g1.x + b1.x;
  y[5] = (v1.y - mean) * inv * g1.y + b1.y;
  y[6] = (v1.z - mean) * inv * g1.z + b1.z;
  y[7] = (v1.w - mean) * inv * g1.w + b1.w;
  if (OUTBF) {
    u16 tmp[8];
#pragma unroll
    for (int e = 0; e < 8; ++e) tmp[e] = f2bf(y[e]);
    *reinterpret_cast<uint4*>((u16*)out + (long)row * 512 + lane * 8) =
        *reinterpret_cast<const uint4*>(tmp);
  } else {
    float* o = (float*)out + (long)row * 512 + lane * 8;
    *reinterpret_cast<float4*>(o) = make_float4(y[0], y[1], y[2], y[3]);
    *reinterpret_cast<float4*>(o + 4) = make_float4(y[4], y[5], y[6], y[7]);
  }
}

// ------------------------------------------------------------------

extern "C" void kernel_launch(void* const* d_in, const int* in_sizes, int n_in,
                              void* d_out, int out_size, void* d_ws, size_t ws_size,
                              hipStream_t stream) {
  const float* in_x = (const float*)d_in[0];
  const float* ln1_g = (const float*)d_in[1];
  const float* ln1_b = (const float*)d_in[2];
  const float* Wqkv = (const float*)d_in[3];
  const float* bqkv = (const float*)d_in[4];
  const float* fsmn_w = (const float*)d_in[5];
  const float* Wout = (const float*)d_in[6];
  const float* bout = (const float*)d_in[7];
  const float* ln2_g = (const float*)d_in[8];
  const float* ln2_b = (const float*)d_in[9];
  const float* W1 = (const float*)d_in[10];
  const float* b1 = (const float*)d_in[11];
  const float* W2 = (const float*)d_in[12];
  const float* b2 = (const float*)d_in[13];
  const float* after_g = (const float*)d_in[14];
  const float* after_b = (const float*)d_in[15];

  const int T = 2048, D = 512, F = 2048, L = 8;

  char* p = (char*)d_ws;
  auto alloc = [&](size_t bytes) {
    char* r = p;
    p += (bytes + 255) & ~size_t(255);
    return r;
  };
  u16* WqkvT = (u16*)alloc(8L * 1536 * 512 * 2);
  u16* WoutT = (u16*)alloc(8L * 512 * 512 * 2);
  u16* W1T = (u16*)alloc(8L * 2048 * 512 * 2);
  u16* W2T = (u16*)alloc(8L * 512 * 2048 * 2);
  float* x = (float*)alloc((long)T * D * 4);
  u16* x1 = (u16*)alloc((long)T * D * 2);
  u16* qkv = (u16*)alloc((long)T * 1536 * 2);
  u16* vT = (u16*)alloc((long)D * T * 2);
  u16* attn = (u16*)alloc((long)T * D * 2);
  u16* hb = (u16*)alloc((long)T * F * 2);
  u16* oPart = (u16*)alloc(4L * T * D * 2);
  float* lPart = (float*)alloc(4L * 8 * T * 4);

  // ---- pre-pass: residual stream + bf16 transposed weights (1 dispatch) ----
  hipMemcpyAsync(x, in_x, (long)T * D * 4, hipMemcpyDeviceToDevice, stream);
  transpose_all<<<dim3(384 * 8, 1, 1), 256, 0, stream>>>(
      Wqkv, WqkvT, Wout, WoutT, W1, W1T, W2, W2T);

  for (int l = 0; l < L; ++l) {
    layernorm_k<1><<<T / 4, 256, 0, stream>>>(x, ln1_g + 512 * l, ln1_b + 512 * l, x1);
    // QKV GEMM + fused vT emit   (BN=64: 768 blocks)
    gemm_bt<2, 2, 1><<<dim3(24, 32, 1), 256, 0, stream>>>(
        x1, 512, WqkvT + (long)l * 1536 * 512, 512, bqkv + 1536 * l,
        qkv, 1536, (float*)nullptr, 0, 0, vT, T, 1536, 512, 1, 1.f, 0);
    // flash attention partials (KV-split 4)
    flash_attn_split<<<dim3(32, 8, 4), 256, 0, stream>>>(qkv, vT, oPart, lPart);
    // combine partials -> attn, and x += fsmn(v)
    attn_norm_fsmn<<<T, 256, 0, stream>>>(oPart, lPart, attn, x, qkv,
                                          fsmn_w + (long)l * 512 * 11);
    // x += attn @ Wout + bout   (BN=64, split-K=4: 1024 blocks)
    gemm_bt<2, 2, 0><<<dim3(8, 32, 4), 256, 0, stream>>>(
        attn, 512, WoutT + (long)l * 512 * 512, 512, bout + 512 * l,
        (u16*)nullptr, 0, x, 512, 1, (u16*)nullptr, T, 512, 512, 4, 1.f, 0);
    layernorm_k<1><<<T / 4, 256, 0, stream>>>(x, ln2_g + 512 * l, ln2_b + 512 * l, x1);
    // hb = relu(x1 @ W1 + b1)   (BN=64: 1024 blocks)
    gemm_bt<2, 2, 0><<<dim3(32, 32, 1), 256, 0, stream>>>(
        x1, 512, W1T + (long)l * 2048 * 512, 512, b1 + 2048 * l,
        hb, 2048, (float*)nullptr, 0, 0, (u16*)nullptr, T, 2048, 512, 1, 1.f, 1);
    // x += hb @ W2 + b2   (BN=64, split-K=4: 1024 blocks)
    gemm_bt<2, 2, 0><<<dim3(8, 32, 4), 256, 0, stream>>>(
        hb, 2048, W2T + (long)l * 512 * 2048, 2048, b2 + 512 * l,
        (u16*)nullptr, 0, x, 512, 1, (u16*)nullptr, T, 512, 2048, 4, 1.f, 0);
  }
  layernorm_k<0><<<T / 4, 256, 0, stream>>>(x, after_g, after_b, (float*)d_out);
}

// Round 21
// 822.032 us; speedup vs baseline: 1.0679x; 1.0101x over previous
//
#include <hip/hip_runtime.h>

using u16 = unsigned short;
using u32 = unsigned int;

typedef __bf16 bf16x8 __attribute__((ext_vector_type(8)));
typedef float f32x4 __attribute__((ext_vector_type(4)));

typedef __attribute__((address_space(3))) u32 as3_u32;
typedef __attribute__((address_space(1))) const u32 as1_u32;

__device__ __forceinline__ u16 f2bf(float f) {
  u32 u = __builtin_bit_cast(u32, f);
  u = u + 0x7FFFu + ((u >> 16) & 1u);  // round-to-nearest-even
  return (u16)(u >> 16);
}
__device__ __forceinline__ float bf2f(u16 h) {
  return __builtin_bit_cast(float, (u32)h << 16);
}

// async global->LDS, 16B per lane; LDS dest = wave-uniform base + lane*16
__device__ __forceinline__ void gload16(const u16* g, u16* l) {
  __builtin_amdgcn_global_load_lds((as1_u32*)g, (as3_u32*)l, 16, 0, 0);
}

// ------------------------------------------------------------------
// All-weights transpose + f32->bf16, single dispatch, 2 tiles/block.
// Pad 67 (bank-conflict-free, verified r19).
// ------------------------------------------------------------------
__global__ __launch_bounds__(256) void transpose_all(
    const float* __restrict__ w0, u16* __restrict__ o0,   // Wqkv 512x1536
    const float* __restrict__ w1, u16* __restrict__ o1,   // Wout 512x512
    const float* __restrict__ w2, u16* __restrict__ o2,   // W1   512x2048
    const float* __restrict__ w3, u16* __restrict__ o3) { // W2  2048x512
  __shared__ u16 tile[2][64][67];
  int id = blockIdx.x;
  const int layer = id / 384;
  int r = id % 384;
  const float* in;
  u16* out;
  int R, C, bx;
  if (r < 96)        { in = w0; out = o0; R = 512;  C = 1536; bx = 24; }
  else if (r < 128)  { r -= 96;  in = w1; out = o1; R = 512;  C = 512;  bx = 8;  }
  else if (r < 256)  { r -= 128; in = w2; out = o2; R = 512;  C = 2048; bx = 32; }
  else               { r -= 256; in = w3; out = o3; R = 2048; C = 512;  bx = 8;  }
  const long zofs = (long)layer * R * C;
  const int tid = threadIdx.x;
  int c0[2], r0[2];
#pragma unroll
  for (int p = 0; p < 2; ++p) {
    int t = r * 2 + p;
    c0[p] = (t % bx) * 64;
    r0[p] = (t / bx) * 64;
  }

#pragma unroll
  for (int k = 0; k < 4; ++k) {
    int it = tid + k * 256;
    int row = it >> 4, c4 = (it & 15) * 4;
#pragma unroll
    for (int p = 0; p < 2; ++p) {
      float4 v = *reinterpret_cast<const float4*>(
          in + zofs + (long)(r0[p] + row) * C + c0[p] + c4);
      tile[p][row][c4 + 0] = f2bf(v.x);
      tile[p][row][c4 + 1] = f2bf(v.y);
      tile[p][row][c4 + 2] = f2bf(v.z);
      tile[p][row][c4 + 3] = f2bf(v.w);
    }
  }
  __syncthreads();

#pragma unroll
  for (int k = 0; k < 2; ++k) {
    int it = tid + k * 256;
    int cc = it >> 3, r8 = (it & 7) * 8;
#pragma unroll
    for (int p = 0; p < 2; ++p) {
      u16 tmp[8];
#pragma unroll
      for (int e = 0; e < 8; ++e) tmp[e] = tile[p][r8 + e][cc];
      *reinterpret_cast<uint4*>(out + zofs + (long)(c0[p] + cc) * R + r0[p] + r8) =
          *reinterpret_cast<const uint4*>(tmp);
    }
  }
}

// ------------------------------------------------------------------
// General bf16 GEMM, B transposed. 2-phase prefetch (dbuf LDS), BK=64,
// 4 waves, MI x NI frags of mfma 16x16x32. gload_lds w16 + XOR swizzle.
// VT=1: blocks with n0>=1024 also emit vT[n-1024][m] via LDS transpose.
// blockIdx.z = K-chunk (split-K, atomicAdd f32 path).
// ------------------------------------------------------------------
template <int MI, int NI, int VT>
__global__ __launch_bounds__(256) void gemm_bt(
    const u16* __restrict__ A, int lda,
    const u16* __restrict__ B, int ldb,
    const float* __restrict__ bias,
    u16* __restrict__ outBf, int ldob,
    float* __restrict__ outF, int ldof, int accF,
    u16* __restrict__ vtOut,
    int M, int N, int K, int kChunks, float scale, int relu) {
  __shared__ u16 As[2][MI * 32 * 64];
  __shared__ u16 Bs[2][NI * 32 * 64];
  __shared__ u16 Ts[VT ? NI * 32 : 1][72];
  const int m0 = blockIdx.y * (MI * 32), n0 = blockIdx.x * (NI * 32);
  const int tid = threadIdx.x, lane = tid & 63, wid = tid >> 6;
  const int wr = (wid >> 1) * (MI * 16), wc = (wid & 1) * (NI * 16);
  const int r16 = lane & 15, kg = lane >> 4;

  const int lrow = lane >> 3;
  const int lchunk = (lane & 7) ^ lrow;

  f32x4 acc[MI][NI];
#pragma unroll
  for (int i = 0; i < MI; ++i)
#pragma unroll
    for (int j = 0; j < NI; ++j) acc[i][j] = f32x4{0.f, 0.f, 0.f, 0.f};

  const int kcs = K / kChunks;
  const int kbase = kcs * blockIdx.z;
  const int nkt = kcs / 64;

  auto STAGE = [&](int b, int k0) {
#pragma unroll
    for (int i = 0; i < MI; ++i) {
      const int r = i * 32 + wid * 8 + lrow;
      gload16(A + (long)(m0 + r) * lda + k0 + lchunk * 8,
              &As[b][wid * 512 + i * 2048]);
    }
#pragma unroll
    for (int j = 0; j < NI; ++j) {
      const int r = j * 32 + wid * 8 + lrow;
      gload16(B + (long)(n0 + r) * ldb + k0 + lchunk * 8,
              &Bs[b][wid * 512 + j * 2048]);
    }
  };

  STAGE(0, kbase);
  __syncthreads();

  for (int kt = 0; kt < nkt; ++kt) {
    const int cur = kt & 1;
    if (kt + 1 < nkt) STAGE(cur ^ 1, kbase + (kt + 1) * 64);

#pragma unroll
    for (int s = 0; s < 2; ++s) {
      bf16x8 af[MI], bfv[NI];
#pragma unroll
      for (int i = 0; i < MI; ++i) {
        const int r = wr + i * 16 + r16;
        af[i] = *reinterpret_cast<const bf16x8*>(
            &As[cur][r * 64 + (((s * 4 + kg) ^ (r & 7)) << 3)]);
      }
#pragma unroll
      for (int j = 0; j < NI; ++j) {
        const int r = wc + j * 16 + r16;
        bfv[j] = *reinterpret_cast<const bf16x8*>(
            &Bs[cur][r * 64 + (((s * 4 + kg) ^ (r & 7)) << 3)]);
      }
      __builtin_amdgcn_s_setprio(1);
#pragma unroll
      for (int i = 0; i < MI; ++i)
#pragma unroll
        for (int j = 0; j < NI; ++j)
          acc[i][j] = __builtin_amdgcn_mfma_f32_16x16x32_bf16(af[i], bfv[j], acc[i][j], 0, 0, 0);
      __builtin_amdgcn_s_setprio(0);
    }
    __syncthreads();
  }

  const int rg = (lane >> 4) * 4;
  const bool doVT = VT && (n0 >= 1024);
#pragma unroll
  for (int i = 0; i < MI; ++i) {
#pragma unroll
    for (int j = 0; j < NI; ++j) {
      int col = n0 + wc + j * 16 + r16;
      float bv = (bias && blockIdx.z == 0) ? bias[col] : 0.f;
#pragma unroll
      for (int r = 0; r < 4; ++r) {
        int row = m0 + wr + i * 16 + rg + r;
        float v = acc[i][j][r] * scale + bv;
        if (outF) {
          long idx = (long)row * ldof + col;
          if (accF) atomicAdd(&outF[idx], v);
          else outF[idx] = v;
        }
        if (outBf) {
          if (relu && v < 0.f) v = 0.f;
          u16 hv = f2bf(v);
          outBf[(long)row * ldob + col] = hv;
          if (doVT) Ts[wc + j * 16 + r16][wr + i * 16 + rg + r] = hv;
        }
      }
    }
  }

  if constexpr (VT) {
    if (doVT) {
      __syncthreads();
      const int d0 = n0 - 1024;
      constexpr int CH = MI * 4;
      constexpr int TOT = NI * 32 * CH;
#pragma unroll
      for (int c = 0; c < TOT / 256; ++c) {
        int idx = tid * (TOT / 256) + c;
        int drow = idx / CH, off = (idx % CH) * 8;
        *reinterpret_cast<uint4*>(vtOut + (long)(d0 + drow) * 2048 + m0 + off) =
            *reinterpret_cast<const uint4*>(&Ts[drow][off]);
      }
    }
  }
}

// ------------------------------------------------------------------
// Flash attention, 8-wave blocks (128 q-rows), no-max softmax.
// K double-buffered, V single-buffered. Grid (16,8,4) = 512 blocks,
// 2 blocks/CU x 8 waves = 16 waves/CU (same occupancy as r20's 4x4),
// but K/V staging traffic HALVED (each staged tile feeds 128 q-rows).
// Per-wave compute identical to the proven 4-wave version.
// ------------------------------------------------------------------
constexpr int AFP = 72;

__global__ __launch_bounds__(512, 2) void flash_attn_split(
    const u16* __restrict__ qkv, const u16* __restrict__ vT,
    u16* __restrict__ oPart, float* __restrict__ lPart) {
  __shared__ u16 Ks[2][64 * AFP];
  __shared__ u16 Vs[64 * AFP];
  __shared__ u16 Ps[8][16 * AFP];
  const int h = blockIdx.y;
  const int q0 = blockIdx.x * 128;
  const int split = blockIdx.z;
  const int tid = threadIdx.x;
  const int lane = tid & 63, wid = tid >> 6;   // wid 0..7
  const int r16 = lane & 15, kg8 = (lane >> 4) * 8;

  bf16x8 qa0, qa1;
  {
    union U { uint4 v; u16 hh[8]; } a, b;
    const u16* qrow = qkv + (long)(q0 + wid * 16 + r16) * 1536 + 64 * h;
    a.v = *reinterpret_cast<const uint4*>(qrow + kg8);
    b.v = *reinterpret_cast<const uint4*>(qrow + 32 + kg8);
#pragma unroll
    for (int i = 0; i < 8; ++i) {
      a.hh[i] = f2bf(bf2f(a.hh[i]) * 0.125f);
      b.hh[i] = f2bf(bf2f(b.hh[i]) * 0.125f);
    }
    qa0 = __builtin_bit_cast(bf16x8, a.v);
    qa1 = __builtin_bit_cast(bf16x8, b.v);
  }

  // staging: 512 threads, 1 uint4 each for K and V
  const int srow = tid >> 3;        // 0..63
  const int scol = (tid & 7) * 8;   // 0..56
  const u16* kgl = qkv + 512 + 64 * h + scol;
  const u16* vgl = vT + (long)(64 * h + srow) * 2048 + scol;

  uint4 kr0, vr0;
  auto LOAD = [&](int g) {
    kr0 = *reinterpret_cast<const uint4*>(kgl + (long)(g * 64 + srow) * 1536);
    vr0 = *reinterpret_cast<const uint4*>(vgl + g * 64);
  };
  auto STOREK = [&](int b) {
    *reinterpret_cast<uint4*>(&Ks[b][srow * AFP + scol]) = kr0;
  };
  auto STOREV = [&]() {
    *reinterpret_cast<uint4*>(&Vs[srow * AFP + scol]) = vr0;
  };

  f32x4 oacc[4];
#pragma unroll
  for (int j = 0; j < 4; ++j) oacc[j] = f32x4{0.f, 0.f, 0.f, 0.f};
  float lsum[4] = {0.f, 0.f, 0.f, 0.f};

  const int g0 = split * 8;
  LOAD(g0);
  STOREK(0);
  STOREV();
  __syncthreads();

  for (int t = 0; t < 8; ++t) {
    const int cur = t & 1;
    if (t < 7) LOAD(g0 + t + 1);

    f32x4 sacc[4];
#pragma unroll
    for (int j = 0; j < 4; ++j) sacc[j] = f32x4{0.f, 0.f, 0.f, 0.f};
    __builtin_amdgcn_s_setprio(1);
#pragma unroll
    for (int j = 0; j < 4; ++j) {
      bf16x8 b0 = *reinterpret_cast<const bf16x8*>(&Ks[cur][(j * 16 + r16) * AFP + kg8]);
      bf16x8 b1 = *reinterpret_cast<const bf16x8*>(&Ks[cur][(j * 16 + r16) * AFP + 32 + kg8]);
      sacc[j] = __builtin_amdgcn_mfma_f32_16x16x32_bf16(qa0, b0, sacc[j], 0, 0, 0);
      sacc[j] = __builtin_amdgcn_mfma_f32_16x16x32_bf16(qa1, b1, sacc[j], 0, 0, 0);
    }
    __builtin_amdgcn_s_setprio(0);

#pragma unroll
    for (int r = 0; r < 4; ++r) {
      float e0 = __expf(sacc[0][r]);
      float e1 = __expf(sacc[1][r]);
      float e2 = __expf(sacc[2][r]);
      float e3 = __expf(sacc[3][r]);
      lsum[r] += (e0 + e1) + (e2 + e3);
      int prow = (lane >> 4) * 4 + r;
      Ps[wid][prow * AFP + r16] = f2bf(e0);
      Ps[wid][prow * AFP + 16 + r16] = f2bf(e1);
      Ps[wid][prow * AFP + 32 + r16] = f2bf(e2);
      Ps[wid][prow * AFP + 48 + r16] = f2bf(e3);
    }

#pragma unroll
    for (int st = 0; st < 2; ++st) {
      bf16x8 pa = *reinterpret_cast<const bf16x8*>(&Ps[wid][r16 * AFP + st * 32 + kg8]);
      __builtin_amdgcn_s_setprio(1);
#pragma unroll
      for (int j = 0; j < 4; ++j) {
        bf16x8 bv = *reinterpret_cast<const bf16x8*>(&Vs[(j * 16 + r16) * AFP + st * 32 + kg8]);
        oacc[j] = __builtin_amdgcn_mfma_f32_16x16x32_bf16(pa, bv, oacc[j], 0, 0, 0);
      }
      __builtin_amdgcn_s_setprio(0);
    }

    if (t < 7) {
      STOREK(cur ^ 1);
      __syncthreads();
      STOREV();
      __syncthreads();
    }
  }

  const int rg = (lane >> 4) * 4;
#pragma unroll
  for (int r = 0; r < 4; ++r) {
    float ls = lsum[r];
#pragma unroll
    for (int o = 1; o < 16; o <<= 1) ls += __shfl_xor(ls, o);
    int row = q0 + wid * 16 + rg + r;
    if (r16 == 0) lPart[(long)(split * 8 + h) * 2048 + row] = ls;
#pragma unroll
    for (int j = 0; j < 4; ++j)
      oPart[(long)split * 2048 * 512 + (long)row * 512 + 64 * h + j * 16 + r16] =
          f2bf(oacc[j][r]);
  }
}

// ------------------------------------------------------------------
// Fused: combine KV-split bf16 partials -> attn bf16, AND x += fsmn(v).
// ------------------------------------------------------------------
__global__ __launch_bounds__(256) void attn_norm_fsmn(
    const u16* __restrict__ oPart, const float* __restrict__ lPart,
    u16* __restrict__ attn, float* __restrict__ x,
    const u16* __restrict__ qkv, const float* __restrict__ fw) {
  const int t = blockIdx.x;
  const int d = threadIdx.x * 2;
  const int h = d >> 6;
  float l = 0.f;
#pragma unroll
  for (int s = 0; s < 4; ++s) l += lPart[(long)(s * 8 + h) * 2048 + t];
  float ox = 0.f, oy = 0.f;
#pragma unroll
  for (int s = 0; s < 4; ++s) {
    const u32 v = *reinterpret_cast<const u32*>(
        oPart + (long)s * 2048 * 512 + (long)t * 512 + d);
    ox += bf2f((u16)v);
    oy += bf2f((u16)(v >> 16));
  }
  const float inv = 1.f / l;
  u16* out = attn + (long)t * 512 + d;
  out[0] = f2bf(ox * inv);
  out[1] = f2bf(oy * inv);

  const u16* v = qkv + 1024 + d;
  float s0 = bf2f(v[(long)t * 1536]);
  float s1 = bf2f(v[(long)t * 1536 + 1]);
#pragma unroll
  for (int j = 0; j < 11; ++j) {
    int ts = t + j - 5;
    if (ts >= 0 && ts < 2048) {
      float w0 = fw[d * 11 + j], w1 = fw[(d + 1) * 11 + j];
      s0 += w0 * bf2f(v[(long)ts * 1536]);
      s1 += w1 * bf2f(v[(long)ts * 1536 + 1]);
    }
  }
  x[(long)t * 512 + d] += s0;
  x[(long)t * 512 + d + 1] += s1;
}

// ------------------------------------------------------------------
// LayerNorm, wave-per-row: 4 rows/block, no LDS, no barriers.
// ------------------------------------------------------------------
template <int OUTBF>
__global__ __launch_bounds__(256) void layernorm_k(
    const float* __restrict__ xin, const float* __restrict__ g,
    const float* __restrict__ bta, void* __restrict__ out) {
  const int lane = threadIdx.x & 63;
  const int row = blockIdx.x * 4 + (threadIdx.x >> 6);
  const float* xr = xin + (long)row * 512 + lane * 8;
  const float4 v0 = *reinterpret_cast<const float4*>(xr);
  const float4 v1 = *reinterpret_cast<const float4*>(xr + 4);
  float s = ((v0.x + v0.y) + (v0.z + v0.w)) + ((v1.x + v1.y) + (v1.z + v1.w));
  float ss = ((v0.x * v0.x + v0.y * v0.y) + (v0.z * v0.z + v0.w * v0.w)) +
             ((v1.x * v1.x + v1.y * v1.y) + (v1.z * v1.z + v1.w * v1.w));
#pragma unroll
  for (int o = 32; o; o >>= 1) {
    s += __shfl_xor(s, o);
    ss += __shfl_xor(ss, o);
  }
  const float mean = s * (1.f / 512.f);
  const float var = ss * (1.f / 512.f) - mean * mean;
  const float inv = rsqrtf(var + 1e-5f);
  const float4 g0 = *reinterpret_cast<const float4*>(g + lane * 8);
  const float4 g1 = *reinterpret_cast<const float4*>(g + lane * 8 + 4);
  const float4 b0 = *reinterpret_cast<const float4*>(bta + lane * 8);
  const float4 b1 = *reinterpret_cast<const float4*>(bta + lane * 8 + 4);
  float y[8];
  y[0] = (v0.x - mean) * inv * g0.x + b0.x;
  y[1] = (v0.y - mean) * inv * g0.y + b0.y;
  y[2] = (v0.z - mean) * inv * g0.z + b0.z;
  y[3] = (v0.w - mean) * inv * g0.w + b0.w;
  y[4] = (v1.x - mean) * inv * g1.x + b1.x;
  y[5] = (v1.y - mean) * inv * g1.y + b1.y;
  y[6] = (v1.z - mean) * inv * g1.z + b1.z;
  y[7] = (v1.w - mean) * inv * g1.w + b1.w;
  if (OUTBF) {
    u16 tmp[8];
#pragma unroll
    for (int e = 0; e < 8; ++e) tmp[e] = f2bf(y[e]);
    *reinterpret_cast<uint4*>((u16*)out + (long)row * 512 + lane * 8) =
        *reinterpret_cast<const uint4*>(tmp);
  } else {
    float* o = (float*)out + (long)row * 512 + lane * 8;
    *reinterpret_cast<float4*>(o) = make_float4(y[0], y[1], y[2], y[3]);
    *reinterpret_cast<float4*>(o + 4) = make_float4(y[4], y[5], y[6], y[7]);
  }
}

// ------------------------------------------------------------------

extern "C" void kernel_launch(void* const* d_in, const int* in_sizes, int n_in,
                              void* d_out, int out_size, void* d_ws, size_t ws_size,
                              hipStream_t stream) {
  const float* in_x = (const float*)d_in[0];
  const float* ln1_g = (const float*)d_in[1];
  const float* ln1_b = (const float*)d_in[2];
  const float* Wqkv = (const float*)d_in[3];
  const float* bqkv = (const float*)d_in[4];
  const float* fsmn_w = (const float*)d_in[5];
  const float* Wout = (const float*)d_in[6];
  const float* bout = (const float*)d_in[7];
  const float* ln2_g = (const float*)d_in[8];
  const float* ln2_b = (const float*)d_in[9];
  const float* W1 = (const float*)d_in[10];
  const float* b1 = (const float*)d_in[11];
  const float* W2 = (const float*)d_in[12];
  const float* b2 = (const float*)d_in[13];
  const float* after_g = (const float*)d_in[14];
  const float* after_b = (const float*)d_in[15];

  const int T = 2048, D = 512, F = 2048, L = 8;

  char* p = (char*)d_ws;
  auto alloc = [&](size_t bytes) {
    char* r = p;
    p += (bytes + 255) & ~size_t(255);
    return r;
  };
  u16* WqkvT = (u16*)alloc(8L * 1536 * 512 * 2);
  u16* WoutT = (u16*)alloc(8L * 512 * 512 * 2);
  u16* W1T = (u16*)alloc(8L * 2048 * 512 * 2);
  u16* W2T = (u16*)alloc(8L * 512 * 2048 * 2);
  float* x = (float*)alloc((long)T * D * 4);
  u16* x1 = (u16*)alloc((long)T * D * 2);
  u16* qkv = (u16*)alloc((long)T * 1536 * 2);
  u16* vT = (u16*)alloc((long)D * T * 2);
  u16* attn = (u16*)alloc((long)T * D * 2);
  u16* hb = (u16*)alloc((long)T * F * 2);
  u16* oPart = (u16*)alloc(4L * T * D * 2);
  float* lPart = (float*)alloc(4L * 8 * T * 4);

  // ---- pre-pass: residual stream + bf16 transposed weights (1 dispatch) ----
  hipMemcpyAsync(x, in_x, (long)T * D * 4, hipMemcpyDeviceToDevice, stream);
  transpose_all<<<dim3(384 * 8, 1, 1), 256, 0, stream>>>(
      Wqkv, WqkvT, Wout, WoutT, W1, W1T, W2, W2T);

  for (int l = 0; l < L; ++l) {
    layernorm_k<1><<<T / 4, 256, 0, stream>>>(x, ln1_g + 512 * l, ln1_b + 512 * l, x1);
    // QKV GEMM + fused vT emit   (BN=64: 768 blocks)
    gemm_bt<2, 2, 1><<<dim3(24, 32, 1), 256, 0, stream>>>(
        x1, 512, WqkvT + (long)l * 1536 * 512, 512, bqkv + 1536 * l,
        qkv, 1536, (float*)nullptr, 0, 0, vT, T, 1536, 512, 1, 1.f, 0);
    // flash attention partials (8-wave blocks, KV-split 4)
    flash_attn_split<<<dim3(16, 8, 4), 512, 0, stream>>>(qkv, vT, oPart, lPart);
    // combine partials -> attn, and x += fsmn(v)
    attn_norm_fsmn<<<T, 256, 0, stream>>>(oPart, lPart, attn, x, qkv,
                                          fsmn_w + (long)l * 512 * 11);
    // x += attn @ Wout + bout   (BN=64, split-K=4: 1024 blocks)
    gemm_bt<2, 2, 0><<<dim3(8, 32, 4), 256, 0, stream>>>(
        attn, 512, WoutT + (long)l * 512 * 512, 512, bout + 512 * l,
        (u16*)nullptr, 0, x, 512, 1, (u16*)nullptr, T, 512, 512, 4, 1.f, 0);
    layernorm_k<1><<<T / 4, 256, 0, stream>>>(x, ln2_g + 512 * l, ln2_b + 512 * l, x1);
    // hb = relu(x1 @ W1 + b1)   (BN=64: 1024 blocks)
    gemm_bt<2, 2, 0><<<dim3(32, 32, 1), 256, 0, stream>>>(
        x1, 512, W1T + (long)l * 2048 * 512, 512, b1 + 2048 * l,
        hb, 2048, (float*)nullptr, 0, 0, (u16*)nullptr, T, 2048, 512, 1, 1.f, 1);
    // x += hb @ W2 + b2   (BN=64, split-K=4: 1024 blocks)
    gemm_bt<2, 2, 0><<<dim3(8, 32, 4), 256, 0, stream>>>(
        hb, 2048, W2T + (long)l * 512 * 2048, 2048, b2 + 512 * l,
        (u16*)nullptr, 0, x, 512, 1, (u16*)nullptr, T, 512, 2048, 4, 1.f, 0);
  }
  layernorm_k<0><<<T / 4, 256, 0, stream>>>(x, after_g, after_b, (float*)d_out);
}